// Round 3
// baseline (648.909 us; speedup 1.0000x reference)
//
#include <hip/hip_runtime.h>
#include <hip/hip_bf16.h>

using f16 = _Float16;
typedef _Float16 f16x8 __attribute__((ext_vector_type(8)));
typedef float f32x4 __attribute__((ext_vector_type(4)));

// Problem constants
constexpr int Bc = 4, Qc = 1024, Dc = 1024, Nh = 16, DHc = 64;
constexpr int BQ = Bc * Qc;      // 4096 rows of w
constexpr int NHEAD = Bc * Nh;   // 64 (b,n) heads
constexpr float ATT_SCALE = 0.125f;

// ---------------- f32 -> f16 copy ----------------
__global__ void k_f2h(const float* __restrict__ src, f16* __restrict__ dst, long n) {
    long i = (long)blockIdx.x * blockDim.x + threadIdx.x;
    if (i < n) dst[i] = (f16)src[i];
}

// ---------------- tiled transpose, src[R][C] -> dst[C][R], output f16 ----------------
template <typename ST>
__global__ void k_transpose(const ST* __restrict__ src, f16* __restrict__ dst,
                            int R, int C, long sStride, long dStride) {
    __shared__ f16 tile[32][33];
    long sb = (long)blockIdx.z * sStride;
    long db = (long)blockIdx.z * dStride;
    int c0 = blockIdx.x * 32, r0 = blockIdx.y * 32;
#pragma unroll
    for (int dy = 0; dy < 32; dy += 8) {
        int r = r0 + threadIdx.y + dy, c = c0 + threadIdx.x;
        tile[threadIdx.y + dy][threadIdx.x] = (f16)(float)src[sb + (long)r * C + c];
    }
    __syncthreads();
#pragma unroll
    for (int dy = 0; dy < 32; dy += 8) {
        int c = c0 + threadIdx.y + dy, r = r0 + threadIdx.x;
        dst[db + (long)c * R + r] = tile[threadIdx.x][threadIdx.y + dy];
    }
}

// ---------------- generic batched NT GEMM: C = A(MxK) * Bt(NxK)^T ----------------
// MFMA f32_16x16x32_f16. A-frag: A[m=lane&15][k=(lane>>4)*8+j]; B symmetric;
// C/D: row=(lane>>4)*4+reg, col=lane&15  (m89/m91/m121-verified mappings).
template <int BM, int BN, int BK, int WROWS, int WCOLS, bool OUT_F32>
__global__ __launch_bounds__(256) void k_gemm_nt(
    const f16* __restrict__ A, const f16* __restrict__ Bt, void* __restrict__ Cv,
    int M, int Ncols, int K, int lda, int ldb, int ldc,
    long strideA, long strideB, long strideC)
{
    constexpr int TM = BM / (WROWS * 16);
    constexpr int TN = BN / (WCOLS * 16);
    __shared__ __align__(16) f16 sA[BM * BK];
    __shared__ __align__(16) f16 sB[BN * BK];

    const int tid = threadIdx.x;
    const int lane = tid & 63, wave = tid >> 6;
    const int wm = wave / WCOLS, wn = wave % WCOLS;
    const int m0 = blockIdx.y * BM, n0 = blockIdx.x * BN;
    A  += (long)blockIdx.z * strideA;
    Bt += (long)blockIdx.z * strideB;

    f32x4 acc[TM][TN] = {};

    const int lrow = lane & 15;
    const int kq = (lane >> 4) * 8;

    for (int k0 = 0; k0 < K; k0 += BK) {
        __syncthreads();
        constexpr int AV = BM * BK / 8;
#pragma unroll
        for (int idx = tid; idx < AV; idx += 256) {
            int r = idx / (BK / 8), c = (idx % (BK / 8)) * 8;
            *(uint4*)&sA[r * BK + c] = *(const uint4*)&A[(long)(m0 + r) * lda + k0 + c];
        }
        constexpr int BV = BN * BK / 8;
#pragma unroll
        for (int idx = tid; idx < BV; idx += 256) {
            int r = idx / (BK / 8), c = (idx % (BK / 8)) * 8;
            *(uint4*)&sB[r * BK + c] = *(const uint4*)&Bt[(long)(n0 + r) * ldb + k0 + c];
        }
        __syncthreads();

        f16x8 af[TM], bfr[TN];
#pragma unroll
        for (int mi = 0; mi < TM; ++mi)
            af[mi] = *(const f16x8*)&sA[(wm * TM * 16 + mi * 16 + lrow) * BK + kq];
#pragma unroll
        for (int ni = 0; ni < TN; ++ni)
            bfr[ni] = *(const f16x8*)&sB[(wn * TN * 16 + ni * 16 + lrow) * BK + kq];
#pragma unroll
        for (int mi = 0; mi < TM; ++mi)
#pragma unroll
            for (int ni = 0; ni < TN; ++ni)
                acc[mi][ni] = __builtin_amdgcn_mfma_f32_16x16x32_f16(af[mi], bfr[ni], acc[mi][ni], 0, 0, 0);
    }

    const int crow = (lane >> 4) * 4;
    const int ccol = lane & 15;
    long cbase = (long)blockIdx.z * strideC;
#pragma unroll
    for (int mi = 0; mi < TM; ++mi)
#pragma unroll
        for (int ni = 0; ni < TN; ++ni)
#pragma unroll
            for (int r = 0; r < 4; ++r) {
                int gm = m0 + wm * TM * 16 + mi * 16 + crow + r;
                int gn = n0 + wn * TN * 16 + ni * 16 + ccol;
                if constexpr (OUT_F32)
                    ((float*)Cv)[cbase + (long)gm * ldc + gn] = acc[mi][ni][r];
                else
                    ((f16*)Cv)[cbase + (long)gm * ldc + gn] = (f16)acc[mi][ni][r];
            }
}

// ---------------- build concatenated Qt/Kt: [h][i][128] ----------------
// Qt[h][i][0:64] = q + r_w_bias ; Qt[..][64:128] = q
// Kt[h][j][0:64] = k           ; Kt[..][64:128] = r_emb[j+1] (0 at j=1023)
__global__ void k_build_qtkt(const f16* __restrict__ qh, const f16* __restrict__ kh,
                             const float* __restrict__ rwb, const float* __restrict__ remb,
                             f16* __restrict__ Qt, f16* __restrict__ Kt) {
    long idx = (long)blockIdx.x * blockDim.x + threadIdx.x;  // 64*1024*128
    int f = idx & 127;
    int i = (int)((idx >> 7) & 1023);
    int h = (int)(idx >> 17);
    int b = h >> 4, n = h & 15;
    long base = ((long)(b * 1024 + i) << 10) + n * 64;
    f16 qv, kv;
    if (f < 64) {
        qv = (f16)((float)qh[base + f] + rwb[n * 64 + f]);
        kv = kh[base + f];
    } else {
        int d = f - 64;
        qv = qh[base + d];
        kv = (i < 1023) ? (f16)remb[((long)(i + 1) * 16 + n) * 64 + d] : (f16)0.0f;
    }
    Qt[idx] = qv;
    Kt[idx] = kv;
}

// ---------------- row softmax with shifted r_bias + scale, fp32 in / f16 out ----------------
__global__ __launch_bounds__(256) void k_softmax(const float* __restrict__ S,
                                                 const float* __restrict__ r_bias,
                                                 f16* __restrict__ P, int h0) {
    const int row = blockIdx.x;        // g*1024 + i
    const int g = row >> 10;
    const int n = (h0 + g) & 15;
    const float* s = S + (long)row * 1024;
    f16* p = P + (long)row * 1024;
    const int tid = threadIdx.x;

    float v[4];
    float mx = -1e30f;
#pragma unroll
    for (int k = 0; k < 4; ++k) {
        int j = tid + k * 256;
        float rb = (j < 1023) ? r_bias[(j + 1) * 16 + n] : 0.0f;
        v[k] = (s[j] + rb) * ATT_SCALE;
        mx = fmaxf(mx, v[k]);
    }
#pragma unroll
    for (int off = 32; off; off >>= 1) mx = fmaxf(mx, __shfl_down(mx, off));
    __shared__ float red1[4];
    if ((tid & 63) == 0) red1[tid >> 6] = mx;
    __syncthreads();
    mx = fmaxf(fmaxf(red1[0], red1[1]), fmaxf(red1[2], red1[3]));

    float sum = 0.0f;
#pragma unroll
    for (int k = 0; k < 4; ++k) { v[k] = __expf(v[k] - mx); sum += v[k]; }
#pragma unroll
    for (int off = 32; off; off >>= 1) sum += __shfl_down(sum, off);
    __shared__ float red2[4];
    if ((tid & 63) == 0) red2[tid >> 6] = sum;
    __syncthreads();
    sum = red2[0] + red2[1] + red2[2] + red2[3];
    float inv = 1.0f / sum;
#pragma unroll
    for (int k = 0; k < 4; ++k) p[tid + k * 256] = (f16)(v[k] * inv);
}

// ---------------- permute av [h][i][64] -> avp [b][i][n*64+d] ----------------
__global__ void k_permute_av(const f16* __restrict__ av, f16* __restrict__ avp) {
    long idx = (long)blockIdx.x * blockDim.x + threadIdx.x;  // 64*1024*64
    int d = idx & 63;
    int i = (int)((idx >> 6) & 1023);
    int h = (int)(idx >> 16);
    int b = h >> 4, n = h & 15;
    avp[((long)(b * 1024 + i) << 10) + n * 64 + d] = av[idx];
}

// ---------------- residual + LayerNorm (f32 inputs, f32 output) ----------------
__global__ __launch_bounds__(256) void k_res_ln(const float* __restrict__ w, const float* __restrict__ ao,
                                                const float* __restrict__ gamma, const float* __restrict__ beta,
                                                float* __restrict__ out) {
    const long base = (long)blockIdx.x * 1024;
    const int tid = threadIdx.x;
    float x[4], s = 0.0f, s2 = 0.0f;
#pragma unroll
    for (int k = 0; k < 4; ++k) {
        int j = tid + k * 256;
        x[k] = w[base + j] + ao[base + j];
        s += x[k];
        s2 += x[k] * x[k];
    }
#pragma unroll
    for (int off = 32; off; off >>= 1) { s += __shfl_down(s, off); s2 += __shfl_down(s2, off); }
    __shared__ float rs[4], rs2[4];
    if ((tid & 63) == 0) { rs[tid >> 6] = s; rs2[tid >> 6] = s2; }
    __syncthreads();
    s = rs[0] + rs[1] + rs[2] + rs[3];
    s2 = rs2[0] + rs2[1] + rs2[2] + rs2[3];
    float mu = s * (1.0f / 1024.0f);
    float var = s2 * (1.0f / 1024.0f) - mu * mu;
    float inv = rsqrtf(var + 1e-5f);
#pragma unroll
    for (int k = 0; k < 4; ++k) {
        int j = tid + k * 256;
        out[base + j] = (x[k] - mu) * inv * gamma[j] + beta[j];
    }
}

extern "C" void kernel_launch(void* const* d_in, const int* in_sizes, int n_in,
                              void* d_out, int out_size, void* d_ws, size_t ws_size,
                              hipStream_t stream) {
    const float* w_in   = (const float*)d_in[0];
    const float* r_emb  = (const float*)d_in[1];
    const float* r_wb   = (const float*)d_in[2];
    const float* r_bias = (const float*)d_in[3];
    const float* Wq     = (const float*)d_in[4];
    const float* Wk     = (const float*)d_in[5];
    const float* Wv     = (const float*)d_in[6];
    const float* Wo     = (const float*)d_in[7];
    const float* ln_g   = (const float*)d_in[8];
    const float* ln_b   = (const float*)d_in[9];
    float* out = (float*)d_out;

    // workspace carve-out (all sizes 256B-aligned)
    char* p = (char*)d_ws;
    auto alloc = [&](size_t bytes) { char* r = p; p += (bytes + 255) & ~(size_t)255; return r; };
    f16*   wh  = (f16*)alloc((size_t)BQ * Dc * 2);          // 8 MB
    f16*   WqT = (f16*)alloc((size_t)Dc * Dc * 2);          // 2 MB
    f16*   WkT = (f16*)alloc((size_t)Dc * Dc * 2);
    f16*   WvT = (f16*)alloc((size_t)Dc * Dc * 2);
    f16*   WoT = (f16*)alloc((size_t)Dc * Dc * 2);
    f16*   qh  = (f16*)alloc((size_t)BQ * Dc * 2);          // 8 MB
    f16*   kh  = (f16*)alloc((size_t)BQ * Dc * 2);
    f16*   vh  = (f16*)alloc((size_t)BQ * Dc * 2);
    f16*   vT  = (f16*)alloc((size_t)BQ * Dc * 2);          // [h][d][j]
    f16*   Qt  = (f16*)alloc((size_t)NHEAD * Qc * 128 * 2); // 16 MB
    f16*   Kt  = (f16*)alloc((size_t)NHEAD * Qc * 128 * 2); // 16 MB
    // aliased buffers (dead-range reuse; liveness: qh/kh dead after build_qtkt,
    // Qt dead after last S-GEMM):
    f16*   av  = qh;                 // [h][i][64], written in chunk loop
    f16*   avp = kh;                 // [b][i][1024]
    float* ao  = (float*)Qt;         // 16 MB fp32
    // S/P chunk buffers sized by remaining workspace
    size_t fixed = (size_t)(p - (char*)d_ws);
    size_t avail = (ws_size > fixed) ? ws_size - fixed : 0;
    int CH = 1;
    for (int c = 16; c >= 1; c >>= 1) {
        size_t need = (size_t)c * Qc * Qc * 4 + (size_t)c * Qc * Qc * 2 + 512;
        if (need <= avail) { CH = c; break; }
    }
    float* Sb = (float*)alloc((size_t)CH * Qc * Qc * 4);
    f16*   Pb = (f16*)alloc((size_t)CH * Qc * Qc * 2);

    // 1. f32->f16 of w
    k_f2h<<<(BQ * Dc) / 256, 256, 0, stream>>>(w_in, wh, (long)BQ * Dc);

    // 2. transpose weights (f32 -> f16)
    dim3 tb(32, 8);
    k_transpose<float><<<dim3(32, 32, 1), tb, 0, stream>>>(Wq, WqT, Dc, Dc, 0, 0);
    k_transpose<float><<<dim3(32, 32, 1), tb, 0, stream>>>(Wk, WkT, Dc, Dc, 0, 0);
    k_transpose<float><<<dim3(32, 32, 1), tb, 0, stream>>>(Wv, WvT, Dc, Dc, 0, 0);
    k_transpose<float><<<dim3(32, 32, 1), tb, 0, stream>>>(Wo, WoT, Dc, Dc, 0, 0);

    // 3. projections: qh/kh/vh = wh @ W*^T   (M=4096,N=1024,K=1024)
    k_gemm_nt<128, 128, 32, 2, 2, false><<<dim3(Dc / 128, BQ / 128, 1), 256, 0, stream>>>(
        wh, WqT, qh, BQ, Dc, Dc, Dc, Dc, Dc, 0, 0, 0);
    k_gemm_nt<128, 128, 32, 2, 2, false><<<dim3(Dc / 128, BQ / 128, 1), 256, 0, stream>>>(
        wh, WkT, kh, BQ, Dc, Dc, Dc, Dc, Dc, 0, 0, 0);
    k_gemm_nt<128, 128, 32, 2, 2, false><<<dim3(Dc / 128, BQ / 128, 1), 256, 0, stream>>>(
        wh, WvT, vh, BQ, Dc, Dc, Dc, Dc, Dc, 0, 0, 0);

    // 4. concatenated Q~/K~ with rel-shift folded into K~
    k_build_qtkt<<<(NHEAD * Qc * 128) / 256, 256, 0, stream>>>(qh, kh, r_wb, r_emb, Qt, Kt);

    // 5. vT: per-b transpose of vh -> [h][d][j]
    k_transpose<f16><<<dim3(32, 32, Bc), tb, 0, stream>>>(vh, vT, Qc, Dc,
                                                          (long)Qc * Dc, (long)Qc * Dc);

    // 6. attention in chunks of CH heads
    for (int ch = 0; ch < NHEAD / CH; ++ch) {
        const f16* Aq = Qt + (long)ch * CH * Qc * 128;
        const f16* Bk = Kt + (long)ch * CH * Qc * 128;
        // S = Q~ @ K~^T  (M=N=1024, K=128), fp32 out
        k_gemm_nt<128, 128, 32, 2, 2, true><<<dim3(Qc / 128, Qc / 128, CH), 256, 0, stream>>>(
            Aq, Bk, Sb, Qc, Qc, 128, 128, 128, Qc,
            (long)Qc * 128, (long)Qc * 128, (long)Qc * Qc);
        // softmax((S + r_bias_shift) * scale)
        k_softmax<<<CH * Qc, 256, 0, stream>>>(Sb, r_bias, Pb, ch * CH);
        // av = P @ V  (M=1024, N=64, K=1024)
        k_gemm_nt<128, 64, 32, 2, 2, false><<<dim3(1, Qc / 128, CH), 256, 0, stream>>>(
            Pb, vT + (long)ch * CH * DHc * Qc, av + (long)ch * CH * Qc * DHc,
            Qc, DHc, Qc, Qc, Qc, DHc,
            (long)Qc * Qc, (long)DHc * Qc, (long)Qc * DHc);
    }

    // 7. reassemble heads: av[h][i][d] -> avp[b][i][n*64+d]
    k_permute_av<<<(NHEAD * Qc * DHc) / 256, 256, 0, stream>>>(av, avp);

    // 8. attn_out = avp @ Wo^T  (fp32 out, into aliased ao)
    k_gemm_nt<128, 128, 32, 2, 2, true><<<dim3(Dc / 128, BQ / 128, 1), 256, 0, stream>>>(
        avp, WoT, ao, BQ, Dc, Dc, Dc, Dc, Dc, 0, 0, 0);

    // 9. out = LayerNorm(w + attn_out), fp32 output
    k_res_ln<<<BQ, 256, 0, stream>>>(w_in, ao, ln_g, ln_b, out);
}

// Round 4
// 401.087 us; speedup vs baseline: 1.6179x; 1.6179x over previous
//
#include <hip/hip_runtime.h>
#include <hip/hip_bf16.h>

using f16 = _Float16;
typedef _Float16 f16x8 __attribute__((ext_vector_type(8)));
typedef float f32x4 __attribute__((ext_vector_type(4)));

// Problem constants
constexpr int Bc = 4, Qc = 1024, Dc = 1024, Nh = 16, DHc = 64;
constexpr int BQ = Bc * Qc;      // 4096 rows of w
constexpr int NHEAD = Bc * Nh;   // 64 (b,n) heads
constexpr float ATT_SCALE = 0.125f;

// ---------------- f32 -> f16 copy ----------------
__global__ void k_f2h(const float* __restrict__ src, f16* __restrict__ dst, long n) {
    long i = (long)blockIdx.x * blockDim.x + threadIdx.x;
    if (i < n) dst[i] = (f16)src[i];
}

// ---------------- tiled transpose, src[R][C] -> dst[C][R], output f16 ----------------
template <typename ST>
__global__ void k_transpose(const ST* __restrict__ src, f16* __restrict__ dst,
                            int R, int C, long sStride, long dStride) {
    __shared__ f16 tile[32][33];
    long sb = (long)blockIdx.z * sStride;
    long db = (long)blockIdx.z * dStride;
    int c0 = blockIdx.x * 32, r0 = blockIdx.y * 32;
#pragma unroll
    for (int dy = 0; dy < 32; dy += 8) {
        int r = r0 + threadIdx.y + dy, c = c0 + threadIdx.x;
        tile[threadIdx.y + dy][threadIdx.x] = (f16)(float)src[sb + (long)r * C + c];
    }
    __syncthreads();
#pragma unroll
    for (int dy = 0; dy < 32; dy += 8) {
        int c = c0 + threadIdx.y + dy, r = r0 + threadIdx.x;
        dst[db + (long)c * R + r] = tile[threadIdx.x][threadIdx.y + dy];
    }
}

// ---------------- generic batched NT GEMM: C = A(MxK) * Bt(NxK)^T ----------------
template <int BM, int BN, int BK, int WROWS, int WCOLS, bool OUT_F32>
__global__ __launch_bounds__(256) void k_gemm_nt(
    const f16* __restrict__ A, const f16* __restrict__ Bt, void* __restrict__ Cv,
    int M, int Ncols, int K, int lda, int ldb, int ldc,
    long strideA, long strideB, long strideC)
{
    constexpr int TM = BM / (WROWS * 16);
    constexpr int TN = BN / (WCOLS * 16);
    __shared__ __align__(16) f16 sA[BM * BK];
    __shared__ __align__(16) f16 sB[BN * BK];

    const int tid = threadIdx.x;
    const int lane = tid & 63, wave = tid >> 6;
    const int wm = wave / WCOLS, wn = wave % WCOLS;
    const int m0 = blockIdx.y * BM, n0 = blockIdx.x * BN;
    A  += (long)blockIdx.z * strideA;
    Bt += (long)blockIdx.z * strideB;

    f32x4 acc[TM][TN] = {};

    const int lrow = lane & 15;
    const int kq = (lane >> 4) * 8;

    for (int k0 = 0; k0 < K; k0 += BK) {
        __syncthreads();
        constexpr int AV = BM * BK / 8;
#pragma unroll
        for (int idx = tid; idx < AV; idx += 256) {
            int r = idx / (BK / 8), c = (idx % (BK / 8)) * 8;
            *(uint4*)&sA[r * BK + c] = *(const uint4*)&A[(long)(m0 + r) * lda + k0 + c];
        }
        constexpr int BV = BN * BK / 8;
#pragma unroll
        for (int idx = tid; idx < BV; idx += 256) {
            int r = idx / (BK / 8), c = (idx % (BK / 8)) * 8;
            *(uint4*)&sB[r * BK + c] = *(const uint4*)&Bt[(long)(n0 + r) * ldb + k0 + c];
        }
        __syncthreads();

        f16x8 af[TM], bfr[TN];
#pragma unroll
        for (int mi = 0; mi < TM; ++mi)
            af[mi] = *(const f16x8*)&sA[(wm * TM * 16 + mi * 16 + lrow) * BK + kq];
#pragma unroll
        for (int ni = 0; ni < TN; ++ni)
            bfr[ni] = *(const f16x8*)&sB[(wn * TN * 16 + ni * 16 + lrow) * BK + kq];
#pragma unroll
        for (int mi = 0; mi < TM; ++mi)
#pragma unroll
            for (int ni = 0; ni < TN; ++ni)
                acc[mi][ni] = __builtin_amdgcn_mfma_f32_16x16x32_f16(af[mi], bfr[ni], acc[mi][ni], 0, 0, 0);
    }

    const int crow = (lane >> 4) * 4;
    const int ccol = lane & 15;
    long cbase = (long)blockIdx.z * strideC;
#pragma unroll
    for (int mi = 0; mi < TM; ++mi)
#pragma unroll
        for (int ni = 0; ni < TN; ++ni)
#pragma unroll
            for (int r = 0; r < 4; ++r) {
                int gm = m0 + wm * TM * 16 + mi * 16 + crow + r;
                int gn = n0 + wn * TN * 16 + ni * 16 + ccol;
                if constexpr (OUT_F32)
                    ((float*)Cv)[cbase + (long)gm * ldc + gn] = acc[mi][ni][r];
                else
                    ((f16*)Cv)[cbase + (long)gm * ldc + gn] = (f16)acc[mi][ni][r];
            }
}

// ---------------- build concatenated Qt/Kt: [h][i][128] ----------------
__global__ void k_build_qtkt(const f16* __restrict__ qh, const f16* __restrict__ kh,
                             const float* __restrict__ rwb, const float* __restrict__ remb,
                             f16* __restrict__ Qt, f16* __restrict__ Kt) {
    long idx = (long)blockIdx.x * blockDim.x + threadIdx.x;  // 64*1024*128
    int f = idx & 127;
    int i = (int)((idx >> 7) & 1023);
    int h = (int)(idx >> 17);
    int b = h >> 4, n = h & 15;
    long base = ((long)(b * 1024 + i) << 10) + n * 64;
    f16 qv, kv;
    if (f < 64) {
        qv = (f16)((float)qh[base + f] + rwb[n * 64 + f]);
        kv = kh[base + f];
    } else {
        int d = f - 64;
        qv = qh[base + d];
        kv = (i < 1023) ? (f16)remb[((long)(i + 1) * 16 + n) * 64 + d] : (f16)0.0f;
    }
    Qt[idx] = qv;
    Kt[idx] = kv;
}

// ---------------- fused flash attention ----------------
// Block: 1 head, 64 Q-rows. Waves 4x1 over rows (16 rows/wave, full j-width)
// so each row's online-softmax state is wave-local. sK aliased as sP.
// LDS rows padded to 136 f16: 16B-aligned ds_read_b128, 2-way banks (free).
__global__ __launch_bounds__(256) void k_flash(
    const f16* __restrict__ Qt, const f16* __restrict__ Kt,
    const f16* __restrict__ vT, const float* __restrict__ r_bias,
    f16* __restrict__ avp)
{
    constexpr int LDL = 136;
    __shared__ __align__(16) f16 sQ[64 * LDL];
    __shared__ __align__(16) f16 sKP[128 * LDL];   // K-tile, then P-tile
    __shared__ __align__(16) f16 sV[64 * LDL];

    const int tid = threadIdx.x, lane = tid & 63, wave = tid >> 6;
    const int i0 = blockIdx.x * 64;
    const int h = blockIdx.y;
    const int b = h >> 4, n = h & 15;

    const f16* Qh = Qt + (long)h * Qc * 128;
    const f16* Kh = Kt + (long)h * Qc * 128;
    const f16* Vh = vT + (long)h * DHc * Qc;

    const int lrow = lane & 15, kq = (lane >> 4) * 8;
    const int crow = (lane >> 4) * 4, ccol = lane & 15;

    // stage Q-tile once (64 rows x 128)
    for (int idx = tid; idx < 64 * 16; idx += 256) {
        int r = idx >> 4, c = (idx & 15) * 8;
        *(uint4*)&sQ[r * LDL + c] = *(const uint4*)&Qh[(long)(i0 + r) * 128 + c];
    }

    float m_i[4], l_i[4];
#pragma unroll
    for (int r = 0; r < 4; ++r) { m_i[r] = -1e30f; l_i[r] = 0.0f; }
    f32x4 o_acc[4] = {};   // 16 rows x 64 d-cols per wave

    for (int j0 = 0; j0 < Qc; j0 += 128) {
        __syncthreads();   // prev PV reads done; sQ visible on first iter
        // stage K-tile (128x128) and V-tile (64 d-rows x 128 j)
        for (int idx = tid; idx < 128 * 16; idx += 256) {
            int r = idx >> 4, c = (idx & 15) * 8;
            *(uint4*)&sKP[r * LDL + c] = *(const uint4*)&Kh[(long)(j0 + r) * 128 + c];
        }
        for (int idx = tid; idx < 64 * 16; idx += 256) {
            int r = idx >> 4, c = (idx & 15) * 8;
            *(uint4*)&sV[r * LDL + c] = *(const uint4*)&Vh[(long)r * Qc + j0 + c];
        }
        __syncthreads();

        // S-tile: wave rows = wave*16, cols = full 128 (TN=8), K-depth 128
        f32x4 s_acc[8] = {};
#pragma unroll
        for (int kc = 0; kc < 4; ++kc) {
            f16x8 aq = *(const f16x8*)&sQ[(wave * 16 + lrow) * LDL + kc * 32 + kq];
            f16x8 bk[8];
#pragma unroll
            for (int ni = 0; ni < 8; ++ni)
                bk[ni] = *(const f16x8*)&sKP[(ni * 16 + lrow) * LDL + kc * 32 + kq];
#pragma unroll
            for (int ni = 0; ni < 8; ++ni)
                s_acc[ni] = __builtin_amdgcn_mfma_f32_16x16x32_f16(aq, bk[ni], s_acc[ni], 0, 0, 0);
        }
        __syncthreads();   // all waves done reading sKP before P overwrite

        // shifted r_bias per owned column
        float rb[8];
#pragma unroll
        for (int ni = 0; ni < 8; ++ni) {
            int j = j0 + ni * 16 + ccol;
            rb[ni] = (j < Qc - 1) ? r_bias[(j + 1) * Nh + n] : 0.0f;
        }

        // online softmax, row = wave*16 + crow + r (wave-local)
#pragma unroll
        for (int r = 0; r < 4; ++r) {
            float vv[8], mx = -1e30f;
#pragma unroll
            for (int ni = 0; ni < 8; ++ni) {
                vv[ni] = (s_acc[ni][r] + rb[ni]) * ATT_SCALE;
                mx = fmaxf(mx, vv[ni]);
            }
#pragma unroll
            for (int msk = 1; msk < 16; msk <<= 1) mx = fmaxf(mx, __shfl_xor(mx, msk));
            float mn = fmaxf(m_i[r], mx);
            float alpha = __expf(m_i[r] - mn);
            float sm = 0.0f;
#pragma unroll
            for (int ni = 0; ni < 8; ++ni) { vv[ni] = __expf(vv[ni] - mn); sm += vv[ni]; }
#pragma unroll
            for (int msk = 1; msk < 16; msk <<= 1) sm += __shfl_xor(sm, msk);
            l_i[r] = l_i[r] * alpha + sm;
            m_i[r] = mn;
#pragma unroll
            for (int ni = 0; ni < 4; ++ni) o_acc[ni][r] *= alpha;
            int prow = wave * 16 + crow + r;
#pragma unroll
            for (int ni = 0; ni < 8; ++ni)
                sKP[prow * LDL + ni * 16 + ccol] = (f16)vv[ni];
        }
        __syncthreads();   // P visible

        // PV: A = P (wave's 16 rows, k=128), B = V (d rows, k=j)
#pragma unroll
        for (int kc = 0; kc < 4; ++kc) {
            f16x8 ap = *(const f16x8*)&sKP[(wave * 16 + lrow) * LDL + kc * 32 + kq];
            f16x8 bv[4];
#pragma unroll
            for (int ni = 0; ni < 4; ++ni)
                bv[ni] = *(const f16x8*)&sV[(ni * 16 + lrow) * LDL + kc * 32 + kq];
#pragma unroll
            for (int ni = 0; ni < 4; ++ni)
                o_acc[ni] = __builtin_amdgcn_mfma_f32_16x16x32_f16(ap, bv[ni], o_acc[ni], 0, 0, 0);
        }
    }

    // epilogue: avp[b][i][n*64+d] = O / l
#pragma unroll
    for (int r = 0; r < 4; ++r) {
        int i = i0 + wave * 16 + crow + r;
        float inv = 1.0f / l_i[r];
#pragma unroll
        for (int ni = 0; ni < 4; ++ni) {
            int d = ni * 16 + ccol;
            avp[((long)(b * Qc + i) << 10) + n * 64 + d] = (f16)(o_acc[ni][r] * inv);
        }
    }
}

// ---------------- residual + LayerNorm (f32 inputs, f32 output) ----------------
__global__ __launch_bounds__(256) void k_res_ln(const float* __restrict__ w, const float* __restrict__ ao,
                                                const float* __restrict__ gamma, const float* __restrict__ beta,
                                                float* __restrict__ out) {
    const long base = (long)blockIdx.x * 1024;
    const int tid = threadIdx.x;
    float x[4], s = 0.0f, s2 = 0.0f;
#pragma unroll
    for (int k = 0; k < 4; ++k) {
        int j = tid + k * 256;
        x[k] = w[base + j] + ao[base + j];
        s += x[k];
        s2 += x[k] * x[k];
    }
#pragma unroll
    for (int off = 32; off; off >>= 1) { s += __shfl_down(s, off); s2 += __shfl_down(s2, off); }
    __shared__ float rs[4], rs2[4];
    if ((tid & 63) == 0) { rs[tid >> 6] = s; rs2[tid >> 6] = s2; }
    __syncthreads();
    s = rs[0] + rs[1] + rs[2] + rs[3];
    s2 = rs2[0] + rs2[1] + rs2[2] + rs2[3];
    float mu = s * (1.0f / 1024.0f);
    float var = s2 * (1.0f / 1024.0f) - mu * mu;
    float inv = rsqrtf(var + 1e-5f);
#pragma unroll
    for (int k = 0; k < 4; ++k) {
        int j = tid + k * 256;
        out[base + j] = (x[k] - mu) * inv * gamma[j] + beta[j];
    }
}

extern "C" void kernel_launch(void* const* d_in, const int* in_sizes, int n_in,
                              void* d_out, int out_size, void* d_ws, size_t ws_size,
                              hipStream_t stream) {
    const float* w_in   = (const float*)d_in[0];
    const float* r_emb  = (const float*)d_in[1];
    const float* r_wb   = (const float*)d_in[2];
    const float* r_bias = (const float*)d_in[3];
    const float* Wq     = (const float*)d_in[4];
    const float* Wk     = (const float*)d_in[5];
    const float* Wv     = (const float*)d_in[6];
    const float* Wo     = (const float*)d_in[7];
    const float* ln_g   = (const float*)d_in[8];
    const float* ln_b   = (const float*)d_in[9];
    float* out = (float*)d_out;

    // workspace carve-out (fixed 80MB)
    char* p = (char*)d_ws;
    auto alloc = [&](size_t bytes) { char* r = p; p += (bytes + 255) & ~(size_t)255; return r; };
    f16*   wh  = (f16*)alloc((size_t)BQ * Dc * 2);          // 8 MB
    f16*   WqT = (f16*)alloc((size_t)Dc * Dc * 2);          // 2 MB
    f16*   WkT = (f16*)alloc((size_t)Dc * Dc * 2);
    f16*   WvT = (f16*)alloc((size_t)Dc * Dc * 2);
    f16*   WoT = (f16*)alloc((size_t)Dc * Dc * 2);
    f16*   qh  = (f16*)alloc((size_t)BQ * Dc * 2);          // 8 MB
    f16*   kh  = (f16*)alloc((size_t)BQ * Dc * 2);
    f16*   vh  = (f16*)alloc((size_t)BQ * Dc * 2);
    f16*   vT  = (f16*)alloc((size_t)BQ * Dc * 2);          // [b][dcol][i]
    f16*   Qt  = (f16*)alloc((size_t)NHEAD * Qc * 128 * 2); // 16 MB
    f16*   Kt  = (f16*)alloc((size_t)NHEAD * Qc * 128 * 2); // 16 MB
    // aliases (liveness-checked): kh dead after build_qtkt; Qt dead after flash
    f16*   avp = kh;                 // [b][i][1024] f16
    float* ao  = (float*)Qt;         // 16 MB fp32

    // 1. f32->f16 of w
    k_f2h<<<(BQ * Dc) / 256, 256, 0, stream>>>(w_in, wh, (long)BQ * Dc);

    // 2. transpose weights (f32 -> f16)
    dim3 tb(32, 8);
    k_transpose<float><<<dim3(32, 32, 1), tb, 0, stream>>>(Wq, WqT, Dc, Dc, 0, 0);
    k_transpose<float><<<dim3(32, 32, 1), tb, 0, stream>>>(Wk, WkT, Dc, Dc, 0, 0);
    k_transpose<float><<<dim3(32, 32, 1), tb, 0, stream>>>(Wv, WvT, Dc, Dc, 0, 0);
    k_transpose<float><<<dim3(32, 32, 1), tb, 0, stream>>>(Wo, WoT, Dc, Dc, 0, 0);

    // 3. projections: qh/kh/vh = wh @ W*^T
    k_gemm_nt<128, 128, 32, 2, 2, false><<<dim3(Dc / 128, BQ / 128, 1), 256, 0, stream>>>(
        wh, WqT, qh, BQ, Dc, Dc, Dc, Dc, Dc, 0, 0, 0);
    k_gemm_nt<128, 128, 32, 2, 2, false><<<dim3(Dc / 128, BQ / 128, 1), 256, 0, stream>>>(
        wh, WkT, kh, BQ, Dc, Dc, Dc, Dc, Dc, 0, 0, 0);
    k_gemm_nt<128, 128, 32, 2, 2, false><<<dim3(Dc / 128, BQ / 128, 1), 256, 0, stream>>>(
        wh, WvT, vh, BQ, Dc, Dc, Dc, Dc, Dc, 0, 0, 0);

    // 4. concatenated Q~/K~ with rel-shift folded into K~
    k_build_qtkt<<<(NHEAD * Qc * 128) / 256, 256, 0, stream>>>(qh, kh, r_wb, r_emb, Qt, Kt);

    // 5. vT: per-b transpose of vh -> [b][dcol][i]
    k_transpose<f16><<<dim3(32, 32, Bc), tb, 0, stream>>>(vh, vT, Qc, Dc,
                                                          (long)Qc * Dc, (long)Qc * Dc);

    // 6. fused attention: S -> online softmax(+r_bias shift) -> PV, writes avp
    k_flash<<<dim3(Qc / 64, NHEAD), 256, 0, stream>>>(Qt, Kt, vT, r_bias, avp);

    // 7. attn_out = avp @ Wo^T (fp32 out, into aliased ao)
    k_gemm_nt<128, 128, 32, 2, 2, true><<<dim3(Dc / 128, BQ / 128, 1), 256, 0, stream>>>(
        avp, WoT, ao, BQ, Dc, Dc, Dc, Dc, Dc, 0, 0, 0);

    // 8. out = LayerNorm(w + attn_out), fp32 output
    k_res_ln<<<BQ, 256, 0, stream>>>(w_in, ao, ln_g, ln_b, out);
}

// Round 5
// 383.963 us; speedup vs baseline: 1.6900x; 1.0446x over previous
//
#include <hip/hip_runtime.h>
#include <hip/hip_bf16.h>

using f16 = _Float16;
typedef _Float16 f16x8 __attribute__((ext_vector_type(8)));
typedef float f32x4 __attribute__((ext_vector_type(4)));

#define AS1 __attribute__((address_space(1)))
#define AS3 __attribute__((address_space(3)))

// Problem constants
constexpr int Bc = 4, Qc = 1024, Dc = 1024, Nh = 16, DHc = 64;
constexpr int BQ = Bc * Qc;      // 4096 rows of w
constexpr int NHEAD = Bc * Nh;   // 64 (b,n) heads
constexpr float ATT_SCALE = 0.125f;

// ---------------- f32 -> f16 copy ----------------
__global__ void k_f2h(const float* __restrict__ src, f16* __restrict__ dst, long n) {
    long i = (long)blockIdx.x * blockDim.x + threadIdx.x;
    if (i < n) dst[i] = (f16)src[i];
}

// ---------------- tiled transpose, src[R][C] -> dst[C][R], output f16 ----------------
template <typename ST>
__global__ void k_transpose(const ST* __restrict__ src, f16* __restrict__ dst,
                            int R, int C, long sStride, long dStride) {
    __shared__ f16 tile[32][33];
    long sb = (long)blockIdx.z * sStride;
    long db = (long)blockIdx.z * dStride;
    int c0 = blockIdx.x * 32, r0 = blockIdx.y * 32;
#pragma unroll
    for (int dy = 0; dy < 32; dy += 8) {
        int r = r0 + threadIdx.y + dy, c = c0 + threadIdx.x;
        tile[threadIdx.y + dy][threadIdx.x] = (f16)(float)src[sb + (long)r * C + c];
    }
    __syncthreads();
#pragma unroll
    for (int dy = 0; dy < 32; dy += 8) {
        int c = c0 + threadIdx.y + dy, r = r0 + threadIdx.x;
        dst[db + (long)c * R + r] = tile[threadIdx.x][threadIdx.y + dy];
    }
}

// ---------------- generic NT GEMM with global_load_lds staging (m97 pattern) ----
// C = A(MxK) * Bt(NxK)^T. sA/sB unpadded row-major BK=32 (64B rows): the
// global_load_lds contiguity requirement (wave-uniform base + lane*16B).
template <int BM, int BN, int BK, int WROWS, int WCOLS, bool OUT_F32>
__global__ __launch_bounds__(256) void k_gemm_nt(
    const f16* __restrict__ A, const f16* __restrict__ Bt, void* __restrict__ Cv,
    int M, int Ncols, int K, int lda, int ldb, int ldc,
    long strideA, long strideB, long strideC)
{
    constexpr int TM = BM / (WROWS * 16);
    constexpr int TN = BN / (WCOLS * 16);
    __shared__ __align__(16) f16 sA[BM * BK];
    __shared__ __align__(16) f16 sB[BN * BK];

    const int tid = threadIdx.x;
    const int lane = tid & 63, wave = tid >> 6;
    const int wm = wave / WCOLS, wn = wave % WCOLS;
    const int m0 = blockIdx.y * BM, n0 = blockIdx.x * BN;
    A  += (long)blockIdx.z * strideA;
    Bt += (long)blockIdx.z * strideB;

    f32x4 acc[TM][TN] = {};

    const int lrow = lane & 15;
    const int kq = (lane >> 4) * 8;
    const int srow = lane >> 2;            // 16 rows per 1KB chunk
    const int scol = (lane & 3) * 8;       // 4 lanes x 8 f16 per 64B row

    for (int k0 = 0; k0 < K; k0 += BK) {
        __syncthreads();
        constexpr int CHA = BM * BK / 512;   // 1KB chunks
#pragma unroll
        for (int ch = 0; ch < CHA / 4; ++ch) {
            int cc = ch * 4 + wave;
            __builtin_amdgcn_global_load_lds(
                (const AS1 void*)(const void*)&A[(long)(m0 + cc * 16 + srow) * lda + k0 + scol],
                (AS3 void*)(void*)&sA[cc * 512], 16, 0, 0);
        }
        constexpr int CHB = BN * BK / 512;
#pragma unroll
        for (int ch = 0; ch < CHB / 4; ++ch) {
            int cc = ch * 4 + wave;
            __builtin_amdgcn_global_load_lds(
                (const AS1 void*)(const void*)&Bt[(long)(n0 + cc * 16 + srow) * ldb + k0 + scol],
                (AS3 void*)(void*)&sB[cc * 512], 16, 0, 0);
        }
        __syncthreads();

        f16x8 af[TM], bfr[TN];
#pragma unroll
        for (int mi = 0; mi < TM; ++mi)
            af[mi] = *(const f16x8*)&sA[(wm * TM * 16 + mi * 16 + lrow) * BK + kq];
#pragma unroll
        for (int ni = 0; ni < TN; ++ni)
            bfr[ni] = *(const f16x8*)&sB[(wn * TN * 16 + ni * 16 + lrow) * BK + kq];
#pragma unroll
        for (int mi = 0; mi < TM; ++mi)
#pragma unroll
            for (int ni = 0; ni < TN; ++ni)
                acc[mi][ni] = __builtin_amdgcn_mfma_f32_16x16x32_f16(af[mi], bfr[ni], acc[mi][ni], 0, 0, 0);
    }

    const int crow = (lane >> 4) * 4;
    const int ccol = lane & 15;
    long cbase = (long)blockIdx.z * strideC;
#pragma unroll
    for (int mi = 0; mi < TM; ++mi)
#pragma unroll
        for (int ni = 0; ni < TN; ++ni)
#pragma unroll
            for (int r = 0; r < 4; ++r) {
                int gm = m0 + wm * TM * 16 + mi * 16 + crow + r;
                int gn = n0 + wn * TN * 16 + ni * 16 + ccol;
                if constexpr (OUT_F32)
                    ((float*)Cv)[cbase + (long)gm * ldc + gn] = acc[mi][ni][r];
                else
                    ((f16*)Cv)[cbase + (long)gm * ldc + gn] = (f16)acc[mi][ni][r];
            }
}

// ---------------- build concatenated Qt/Kt: [h][i][128] ----------------
__global__ void k_build_qtkt(const f16* __restrict__ qh, const f16* __restrict__ kh,
                             const float* __restrict__ rwb, const float* __restrict__ remb,
                             f16* __restrict__ Qt, f16* __restrict__ Kt) {
    long idx = (long)blockIdx.x * blockDim.x + threadIdx.x;  // 64*1024*128
    int f = idx & 127;
    int i = (int)((idx >> 7) & 1023);
    int h = (int)(idx >> 17);
    int b = h >> 4, n = h & 15;
    long base = ((long)(b * 1024 + i) << 10) + n * 64;
    f16 qv, kv;
    if (f < 64) {
        qv = (f16)((float)qh[base + f] + rwb[n * 64 + f]);
        kv = kh[base + f];
    } else {
        int d = f - 64;
        qv = qh[base + d];
        kv = (i < 1023) ? (f16)remb[((long)(i + 1) * 16 + n) * 64 + d] : (f16)0.0f;
    }
    Qt[idx] = qv;
    Kt[idx] = kv;
}

// ---------------- fused flash attention ----------------
// Block: 1 head, 128 Q-rows; wave w owns rows [w*32, w*32+32) (2 tiles of 16)
// so online-softmax state stays wave-local. Q frags in registers (no sQ).
// sKP: K-tile then P-tile (both 128x136). P write->read is wave-local rows,
// so no barrier between softmax and PV. 3 barriers/iter.
__global__ __launch_bounds__(256, 3) void k_flash(
    const f16* __restrict__ Qt, const f16* __restrict__ Kt,
    const f16* __restrict__ vT, const float* __restrict__ r_bias,
    f16* __restrict__ avp)
{
    constexpr int LDL = 136;
    __shared__ __align__(16) f16 sKP[128 * LDL];   // K-tile, then P-tile
    __shared__ __align__(16) f16 sV[64 * LDL];

    const int tid = threadIdx.x, lane = tid & 63, wave = tid >> 6;
    const int i0 = blockIdx.x * 128;
    const int h = blockIdx.y;
    const int b = h >> 4, n = h & 15;

    const f16* Qh = Qt + (long)h * Qc * 128;
    const f16* Kh = Kt + (long)h * Qc * 128;
    const f16* Vh = vT + (long)h * DHc * Qc;

    const int lrow = lane & 15, kq = (lane >> 4) * 8;
    const int crow = (lane >> 4) * 4, ccol = lane & 15;

    // Q fragments in registers: rows i0 + wave*32 + t*16 + lrow, k = kc*32+kq
    f16x8 aq[2][4];
#pragma unroll
    for (int t = 0; t < 2; ++t)
#pragma unroll
        for (int kc = 0; kc < 4; ++kc)
            aq[t][kc] = *(const f16x8*)&Qh[(long)(i0 + wave * 32 + t * 16 + lrow) * 128 + kc * 32 + kq];

    float m_i[2][4], l_i[2][4];
#pragma unroll
    for (int t = 0; t < 2; ++t)
#pragma unroll
        for (int r = 0; r < 4; ++r) { m_i[t][r] = -1e30f; l_i[t][r] = 0.0f; }
    f32x4 o_acc[2][4] = {};   // per wave: 32 rows x 64 d-cols

    for (int j0 = 0; j0 < Qc; j0 += 128) {
        __syncthreads();   // prev iter's K/P/V reads complete before restage
        for (int idx = tid; idx < 128 * 16; idx += 256) {
            int r = idx >> 4, c = (idx & 15) * 8;
            *(uint4*)&sKP[r * LDL + c] = *(const uint4*)&Kh[(long)(j0 + r) * 128 + c];
        }
        for (int idx = tid; idx < 64 * 16; idx += 256) {
            int r = idx >> 4, c = (idx & 15) * 8;
            *(uint4*)&sV[r * LDL + c] = *(const uint4*)&Vh[(long)r * Qc + j0 + c];
        }
        __syncthreads();

        // S-tile: 32 rows (2 tiles) x 128 cols, K-depth 128
        f32x4 s_acc[2][8] = {};
#pragma unroll
        for (int kc = 0; kc < 4; ++kc)
#pragma unroll
            for (int ni = 0; ni < 8; ++ni) {
                f16x8 bk = *(const f16x8*)&sKP[(ni * 16 + lrow) * LDL + kc * 32 + kq];
                s_acc[0][ni] = __builtin_amdgcn_mfma_f32_16x16x32_f16(aq[0][kc], bk, s_acc[0][ni], 0, 0, 0);
                s_acc[1][ni] = __builtin_amdgcn_mfma_f32_16x16x32_f16(aq[1][kc], bk, s_acc[1][ni], 0, 0, 0);
            }
        __syncthreads();   // all waves done reading K before P overwrite

        float rb[8];
#pragma unroll
        for (int ni = 0; ni < 8; ++ni) {
            int j = j0 + ni * 16 + ccol;
            rb[ni] = (j < Qc - 1) ? r_bias[(j + 1) * Nh + n] : 0.0f;
        }

        // online softmax per owned row (wave-local), write P to sKP
#pragma unroll
        for (int t = 0; t < 2; ++t)
#pragma unroll
            for (int r = 0; r < 4; ++r) {
                float vv[8], mx = -1e30f;
#pragma unroll
                for (int ni = 0; ni < 8; ++ni) {
                    vv[ni] = (s_acc[t][ni][r] + rb[ni]) * ATT_SCALE;
                    mx = fmaxf(mx, vv[ni]);
                }
#pragma unroll
                for (int msk = 1; msk < 16; msk <<= 1) mx = fmaxf(mx, __shfl_xor(mx, msk));
                float mn = fmaxf(m_i[t][r], mx);
                float alpha = __expf(m_i[t][r] - mn);
                float sm = 0.0f;
#pragma unroll
                for (int ni = 0; ni < 8; ++ni) { vv[ni] = __expf(vv[ni] - mn); sm += vv[ni]; }
#pragma unroll
                for (int msk = 1; msk < 16; msk <<= 1) sm += __shfl_xor(sm, msk);
                l_i[t][r] = l_i[t][r] * alpha + sm;
                m_i[t][r] = mn;
#pragma unroll
                for (int ni = 0; ni < 4; ++ni) o_acc[t][ni][r] *= alpha;
                int prow = wave * 32 + t * 16 + crow + r;
#pragma unroll
                for (int ni = 0; ni < 8; ++ni)
                    sKP[prow * LDL + ni * 16 + ccol] = (f16)vv[ni];
            }
        // no barrier: each wave reads only its own P rows (lgkmcnt ordering)

        // PV: A = P (own 32 rows, k=128), B = V^T (64 d-rows, k=j)
#pragma unroll
        for (int kc = 0; kc < 4; ++kc) {
            f16x8 ap0 = *(const f16x8*)&sKP[(wave * 32 + lrow) * LDL + kc * 32 + kq];
            f16x8 ap1 = *(const f16x8*)&sKP[(wave * 32 + 16 + lrow) * LDL + kc * 32 + kq];
#pragma unroll
            for (int ni = 0; ni < 4; ++ni) {
                f16x8 bv = *(const f16x8*)&sV[(ni * 16 + lrow) * LDL + kc * 32 + kq];
                o_acc[0][ni] = __builtin_amdgcn_mfma_f32_16x16x32_f16(ap0, bv, o_acc[0][ni], 0, 0, 0);
                o_acc[1][ni] = __builtin_amdgcn_mfma_f32_16x16x32_f16(ap1, bv, o_acc[1][ni], 0, 0, 0);
            }
        }
    }

    // epilogue: avp[b][i][n*64+d] = O / l
#pragma unroll
    for (int t = 0; t < 2; ++t)
#pragma unroll
        for (int r = 0; r < 4; ++r) {
            int i = i0 + wave * 32 + t * 16 + crow + r;
            float inv = 1.0f / l_i[t][r];
#pragma unroll
            for (int ni = 0; ni < 4; ++ni) {
                int d = ni * 16 + ccol;
                avp[((long)(b * Qc + i) << 10) + n * 64 + d] = (f16)(o_acc[t][ni][r] * inv);
            }
        }
}

// ---------------- residual + LayerNorm (f32 inputs, f32 output) ----------------
__global__ __launch_bounds__(256) void k_res_ln(const float* __restrict__ w, const float* __restrict__ ao,
                                                const float* __restrict__ gamma, const float* __restrict__ beta,
                                                float* __restrict__ out) {
    const long base = (long)blockIdx.x * 1024;
    const int tid = threadIdx.x;
    float x[4], s = 0.0f, s2 = 0.0f;
#pragma unroll
    for (int k = 0; k < 4; ++k) {
        int j = tid + k * 256;
        x[k] = w[base + j] + ao[base + j];
        s += x[k];
        s2 += x[k] * x[k];
    }
#pragma unroll
    for (int off = 32; off; off >>= 1) { s += __shfl_down(s, off); s2 += __shfl_down(s2, off); }
    __shared__ float rs[4], rs2[4];
    if ((tid & 63) == 0) { rs[tid >> 6] = s; rs2[tid >> 6] = s2; }
    __syncthreads();
    s = rs[0] + rs[1] + rs[2] + rs[3];
    s2 = rs2[0] + rs2[1] + rs2[2] + rs2[3];
    float mu = s * (1.0f / 1024.0f);
    float var = s2 * (1.0f / 1024.0f) - mu * mu;
    float inv = rsqrtf(var + 1e-5f);
#pragma unroll
    for (int k = 0; k < 4; ++k) {
        int j = tid + k * 256;
        out[base + j] = (x[k] - mu) * inv * gamma[j] + beta[j];
    }
}

extern "C" void kernel_launch(void* const* d_in, const int* in_sizes, int n_in,
                              void* d_out, int out_size, void* d_ws, size_t ws_size,
                              hipStream_t stream) {
    const float* w_in   = (const float*)d_in[0];
    const float* r_emb  = (const float*)d_in[1];
    const float* r_wb   = (const float*)d_in[2];
    const float* r_bias = (const float*)d_in[3];
    const float* Wq     = (const float*)d_in[4];
    const float* Wk     = (const float*)d_in[5];
    const float* Wv     = (const float*)d_in[6];
    const float* Wo     = (const float*)d_in[7];
    const float* ln_g   = (const float*)d_in[8];
    const float* ln_b   = (const float*)d_in[9];
    float* out = (float*)d_out;

    // workspace carve-out (fixed 80MB)
    char* p = (char*)d_ws;
    auto alloc = [&](size_t bytes) { char* r = p; p += (bytes + 255) & ~(size_t)255; return r; };
    f16*   wh  = (f16*)alloc((size_t)BQ * Dc * 2);          // 8 MB
    f16*   WqT = (f16*)alloc((size_t)Dc * Dc * 2);          // 2 MB
    f16*   WkT = (f16*)alloc((size_t)Dc * Dc * 2);
    f16*   WvT = (f16*)alloc((size_t)Dc * Dc * 2);
    f16*   WoT = (f16*)alloc((size_t)Dc * Dc * 2);
    f16*   qh  = (f16*)alloc((size_t)BQ * Dc * 2);          // 8 MB
    f16*   kh  = (f16*)alloc((size_t)BQ * Dc * 2);
    f16*   vh  = (f16*)alloc((size_t)BQ * Dc * 2);
    f16*   vT  = (f16*)alloc((size_t)BQ * Dc * 2);          // [b][dcol][i]
    f16*   Qt  = (f16*)alloc((size_t)NHEAD * Qc * 128 * 2); // 16 MB
    f16*   Kt  = (f16*)alloc((size_t)NHEAD * Qc * 128 * 2); // 16 MB
    // aliases (liveness-checked): kh dead after build_qtkt; Qt dead after flash
    f16*   avp = kh;                 // [b][i][1024] f16
    float* ao  = (float*)Qt;         // 16 MB fp32

    // 1. f32->f16 of w
    k_f2h<<<(BQ * Dc) / 256, 256, 0, stream>>>(w_in, wh, (long)BQ * Dc);

    // 2. transpose weights (f32 -> f16)
    dim3 tb(32, 8);
    k_transpose<float><<<dim3(32, 32, 1), tb, 0, stream>>>(Wq, WqT, Dc, Dc, 0, 0);
    k_transpose<float><<<dim3(32, 32, 1), tb, 0, stream>>>(Wk, WkT, Dc, Dc, 0, 0);
    k_transpose<float><<<dim3(32, 32, 1), tb, 0, stream>>>(Wv, WvT, Dc, Dc, 0, 0);
    k_transpose<float><<<dim3(32, 32, 1), tb, 0, stream>>>(Wo, WoT, Dc, Dc, 0, 0);

    // 3. projections: qh/kh/vh = wh @ W*^T
    k_gemm_nt<128, 128, 32, 2, 2, false><<<dim3(Dc / 128, BQ / 128, 1), 256, 0, stream>>>(
        wh, WqT, qh, BQ, Dc, Dc, Dc, Dc, Dc, 0, 0, 0);
    k_gemm_nt<128, 128, 32, 2, 2, false><<<dim3(Dc / 128, BQ / 128, 1), 256, 0, stream>>>(
        wh, WkT, kh, BQ, Dc, Dc, Dc, Dc, Dc, 0, 0, 0);
    k_gemm_nt<128, 128, 32, 2, 2, false><<<dim3(Dc / 128, BQ / 128, 1), 256, 0, stream>>>(
        wh, WvT, vh, BQ, Dc, Dc, Dc, Dc, Dc, 0, 0, 0);

    // 4. concatenated Q~/K~ with rel-shift folded into K~
    k_build_qtkt<<<(NHEAD * Qc * 128) / 256, 256, 0, stream>>>(qh, kh, r_wb, r_emb, Qt, Kt);

    // 5. vT: per-b transpose of vh -> [b][dcol][i]
    k_transpose<f16><<<dim3(32, 32, Bc), tb, 0, stream>>>(vh, vT, Qc, Dc,
                                                          (long)Qc * Dc, (long)Qc * Dc);

    // 6. fused attention: S -> online softmax(+r_bias shift) -> PV, writes avp
    k_flash<<<dim3(Qc / 128, NHEAD), 256, 0, stream>>>(Qt, Kt, vT, r_bias, avp);

    // 7. attn_out = avp @ Wo^T (fp32 out, into aliased ao)
    k_gemm_nt<128, 128, 32, 2, 2, true><<<dim3(Dc / 128, BQ / 128, 1), 256, 0, stream>>>(
        avp, WoT, ao, BQ, Dc, Dc, Dc, Dc, Dc, 0, 0, 0);

    // 8. out = LayerNorm(w + attn_out), fp32 output
    k_res_ln<<<BQ, 256, 0, stream>>>(w_in, ao, ln_g, ln_b, out);
}

// Round 6
// 334.512 us; speedup vs baseline: 1.9399x; 1.1478x over previous
//
#include <hip/hip_runtime.h>
#include <hip/hip_bf16.h>

using f16 = _Float16;
typedef _Float16 f16x8 __attribute__((ext_vector_type(8)));
typedef float f32x4 __attribute__((ext_vector_type(4)));

#define AS1 __attribute__((address_space(1)))
#define AS3 __attribute__((address_space(3)))

// Problem constants
constexpr int Bc = 4, Qc = 1024, Dc = 1024, Nh = 16, DHc = 64;
constexpr int BQ = Bc * Qc;      // 4096 rows of w
constexpr int NHEAD = Bc * Nh;   // 64 (b,n) heads
constexpr float ATT_SCALE = 0.125f;

// ---------------- f32 -> f16, 8 elems/thread ----------------
__global__ void k_f2h(const float* __restrict__ src, f16* __restrict__ dst) {
    long i8 = ((long)blockIdx.x * blockDim.x + threadIdx.x) * 8;
    float4 a = *(const float4*)&src[i8];
    float4 b = *(const float4*)&src[i8 + 4];
    f16x8 o = { (f16)a.x, (f16)a.y, (f16)a.z, (f16)a.w,
                (f16)b.x, (f16)b.y, (f16)b.z, (f16)b.w };
    *(f16x8*)&dst[i8] = o;
}

// ---------------- merged 4-way weight transpose: src[z][R][C] -> dst[z][C][R] f16 ----------------
struct Ptr4 { const float* p[4]; };
__global__ void k_transpose4(Ptr4 srcs, f16* __restrict__ dst) {
    __shared__ f16 tile[32][33];
    const float* src = srcs.p[blockIdx.z];
    f16* d = dst + (long)blockIdx.z * Dc * Dc;
    int c0 = blockIdx.x * 32, r0 = blockIdx.y * 32;
#pragma unroll
    for (int dy = 0; dy < 32; dy += 8) {
        int r = r0 + threadIdx.y + dy, c = c0 + threadIdx.x;
        tile[threadIdx.y + dy][threadIdx.x] = (f16)src[(long)r * Dc + c];
    }
    __syncthreads();
#pragma unroll
    for (int dy = 0; dy < 32; dy += 8) {
        int c = c0 + threadIdx.y + dy, r = r0 + threadIdx.x;
        d[(long)c * Dc + r] = tile[threadIdx.x][threadIdx.y + dy];
    }
}

// ---------------- f16 transpose (for vT) ----------------
__global__ void k_transpose_h(const f16* __restrict__ src, f16* __restrict__ dst,
                              int R, int C, long sStride, long dStride) {
    __shared__ f16 tile[32][33];
    long sb = (long)blockIdx.z * sStride;
    long db = (long)blockIdx.z * dStride;
    int c0 = blockIdx.x * 32, r0 = blockIdx.y * 32;
#pragma unroll
    for (int dy = 0; dy < 32; dy += 8) {
        int r = r0 + threadIdx.y + dy, c = c0 + threadIdx.x;
        tile[threadIdx.y + dy][threadIdx.x] = src[sb + (long)r * C + c];
    }
    __syncthreads();
#pragma unroll
    for (int dy = 0; dy < 32; dy += 8) {
        int c = c0 + threadIdx.y + dy, r = r0 + threadIdx.x;
        dst[db + (long)c * R + r] = tile[threadIdx.x][threadIdx.y + dy];
    }
}

// ---------------- generic NT GEMM with global_load_lds staging (m97 pattern) ----
template <int BM, int BN, int BK, int WROWS, int WCOLS, bool OUT_F32>
__global__ __launch_bounds__(256) void k_gemm_nt(
    const f16* __restrict__ A, const f16* __restrict__ Bt, void* __restrict__ Cv,
    int M, int Ncols, int K, int lda, int ldb, int ldc,
    long strideA, long strideB, long strideC)
{
    constexpr int TM = BM / (WROWS * 16);
    constexpr int TN = BN / (WCOLS * 16);
    __shared__ __align__(16) f16 sA[BM * BK];
    __shared__ __align__(16) f16 sB[BN * BK];

    const int tid = threadIdx.x;
    const int lane = tid & 63, wave = tid >> 6;
    const int wm = wave / WCOLS, wn = wave % WCOLS;
    const int m0 = blockIdx.y * BM, n0 = blockIdx.x * BN;
    A  += (long)blockIdx.z * strideA;
    Bt += (long)blockIdx.z * strideB;

    f32x4 acc[TM][TN] = {};

    const int lrow = lane & 15;
    const int kq = (lane >> 4) * 8;
    const int srow = lane >> 2;            // 16 rows per 1KB chunk
    const int scol = (lane & 3) * 8;       // 4 lanes x 8 f16 per 64B row

    for (int k0 = 0; k0 < K; k0 += BK) {
        __syncthreads();
        constexpr int CHA = BM * BK / 512;   // 1KB chunks
#pragma unroll
        for (int ch = 0; ch < CHA / 4; ++ch) {
            int cc = ch * 4 + wave;
            __builtin_amdgcn_global_load_lds(
                (const AS1 void*)(const void*)&A[(long)(m0 + cc * 16 + srow) * lda + k0 + scol],
                (AS3 void*)(void*)&sA[cc * 512], 16, 0, 0);
        }
        constexpr int CHB = BN * BK / 512;
#pragma unroll
        for (int ch = 0; ch < CHB / 4; ++ch) {
            int cc = ch * 4 + wave;
            __builtin_amdgcn_global_load_lds(
                (const AS1 void*)(const void*)&Bt[(long)(n0 + cc * 16 + srow) * ldb + k0 + scol],
                (AS3 void*)(void*)&sB[cc * 512], 16, 0, 0);
        }
        __syncthreads();

        f16x8 af[TM], bfr[TN];
#pragma unroll
        for (int mi = 0; mi < TM; ++mi)
            af[mi] = *(const f16x8*)&sA[(wm * TM * 16 + mi * 16 + lrow) * BK + kq];
#pragma unroll
        for (int ni = 0; ni < TN; ++ni)
            bfr[ni] = *(const f16x8*)&sB[(wn * TN * 16 + ni * 16 + lrow) * BK + kq];
#pragma unroll
        for (int mi = 0; mi < TM; ++mi)
#pragma unroll
            for (int ni = 0; ni < TN; ++ni)
                acc[mi][ni] = __builtin_amdgcn_mfma_f32_16x16x32_f16(af[mi], bfr[ni], acc[mi][ni], 0, 0, 0);
    }

    const int crow = (lane >> 4) * 4;
    const int ccol = lane & 15;
    long cbase = (long)blockIdx.z * strideC;
#pragma unroll
    for (int mi = 0; mi < TM; ++mi)
#pragma unroll
        for (int ni = 0; ni < TN; ++ni)
#pragma unroll
            for (int r = 0; r < 4; ++r) {
                int gm = m0 + wm * TM * 16 + mi * 16 + crow + r;
                int gn = n0 + wn * TN * 16 + ni * 16 + ccol;
                if constexpr (OUT_F32)
                    ((float*)Cv)[cbase + (long)gm * ldc + gn] = acc[mi][ni][r];
                else
                    ((f16*)Cv)[cbase + (long)gm * ldc + gn] = (f16)acc[mi][ni][r];
            }
}

// ---------------- build concatenated Qt/Kt: [h][i][128], 8 elems/thread ----------------
// Qt[h][i][0:64] = q + r_w_bias ; Qt[..][64:128] = q
// Kt[h][j][0:64] = k           ; Kt[..][64:128] = r_emb[j+1] (0 at j=1023)
__global__ void k_build_qtkt(const f16* __restrict__ qh, const f16* __restrict__ kh,
                             const float* __restrict__ rwb, const float* __restrict__ remb,
                             f16* __restrict__ Qt, f16* __restrict__ Kt) {
    long gid = (long)blockIdx.x * blockDim.x + threadIdx.x;  // 64*1024*16
    int f0 = (int)(gid & 15) * 8;
    int i = (int)((gid >> 4) & 1023);
    int h = (int)(gid >> 14);
    int b = h >> 4, n = h & 15;
    long base = ((long)(b * 1024 + i) << 10) + n * 64;
    long obase = ((long)h << 17) + (i << 7) + f0;
    f16x8 qv, kv;
    if (f0 < 64) {
        f16x8 q8 = *(const f16x8*)&qh[base + f0];
        f16x8 k8 = *(const f16x8*)&kh[base + f0];
        float4 w0 = *(const float4*)&rwb[n * 64 + f0];
        float4 w1 = *(const float4*)&rwb[n * 64 + f0 + 4];
        qv[0] = (f16)((float)q8[0] + w0.x); qv[1] = (f16)((float)q8[1] + w0.y);
        qv[2] = (f16)((float)q8[2] + w0.z); qv[3] = (f16)((float)q8[3] + w0.w);
        qv[4] = (f16)((float)q8[4] + w1.x); qv[5] = (f16)((float)q8[5] + w1.y);
        qv[6] = (f16)((float)q8[6] + w1.z); qv[7] = (f16)((float)q8[7] + w1.w);
        kv = k8;
    } else {
        int d0 = f0 - 64;
        qv = *(const f16x8*)&qh[base + d0];
        if (i < 1023) {
            const float* rp = &remb[((long)(i + 1) * 16 + n) * 64 + d0];
            float4 r0 = *(const float4*)rp;
            float4 r1 = *(const float4*)(rp + 4);
            kv[0] = (f16)r0.x; kv[1] = (f16)r0.y; kv[2] = (f16)r0.z; kv[3] = (f16)r0.w;
            kv[4] = (f16)r1.x; kv[5] = (f16)r1.y; kv[6] = (f16)r1.z; kv[7] = (f16)r1.w;
        } else {
            kv = f16x8{};
        }
    }
    *(f16x8*)&Qt[obase] = qv;
    *(f16x8*)&Kt[obase] = kv;
}

// ---------------- fused flash attention ----------------
// Block: 1 head, 64 Q-rows; wave w owns rows [w*16, w*16+16) so online-softmax
// state is wave-local. Q frags in registers (no sQ; live VGPR ~110, no spill).
// sKP: K-tile then P-tile (128x136). P write->read wave-local (no barrier).
__global__ __launch_bounds__(256, 3) void k_flash(
    const f16* __restrict__ Qt, const f16* __restrict__ Kt,
    const f16* __restrict__ vT, const float* __restrict__ r_bias,
    f16* __restrict__ avp)
{
    constexpr int LDL = 136;
    __shared__ __align__(16) f16 sKP[128 * LDL];   // K-tile, then P-tile
    __shared__ __align__(16) f16 sV[64 * LDL];

    const int tid = threadIdx.x, lane = tid & 63, wave = tid >> 6;
    const int i0 = blockIdx.x * 64;
    const int h = blockIdx.y;
    const int b = h >> 4, n = h & 15;

    const f16* Qh = Qt + (long)h * Qc * 128;
    const f16* Kh = Kt + (long)h * Qc * 128;
    const f16* Vh = vT + (long)h * DHc * Qc;

    const int lrow = lane & 15, kq = (lane >> 4) * 8;
    const int crow = (lane >> 4) * 4, ccol = lane & 15;

    // Q fragments in registers: row i0 + wave*16 + lrow, k = kc*32+kq
    f16x8 aq[4];
#pragma unroll
    for (int kc = 0; kc < 4; ++kc)
        aq[kc] = *(const f16x8*)&Qh[(long)(i0 + wave * 16 + lrow) * 128 + kc * 32 + kq];

    float m_i[4], l_i[4];
#pragma unroll
    for (int r = 0; r < 4; ++r) { m_i[r] = -1e30f; l_i[r] = 0.0f; }
    f32x4 o_acc[4] = {};   // 16 rows x 64 d-cols per wave

    for (int j0 = 0; j0 < Qc; j0 += 128) {
        __syncthreads();   // prev iter's P/V reads complete before restage
        for (int idx = tid; idx < 128 * 16; idx += 256) {
            int r = idx >> 4, c = (idx & 15) * 8;
            *(uint4*)&sKP[r * LDL + c] = *(const uint4*)&Kh[(long)(j0 + r) * 128 + c];
        }
        for (int idx = tid; idx < 64 * 16; idx += 256) {
            int r = idx >> 4, c = (idx & 15) * 8;
            *(uint4*)&sV[r * LDL + c] = *(const uint4*)&Vh[(long)r * Qc + j0 + c];
        }
        __syncthreads();

        // S-tile: 16 rows x 128 cols, K-depth 128
        f32x4 s_acc[8] = {};
#pragma unroll
        for (int kc = 0; kc < 4; ++kc)
#pragma unroll
            for (int ni = 0; ni < 8; ++ni) {
                f16x8 bk = *(const f16x8*)&sKP[(ni * 16 + lrow) * LDL + kc * 32 + kq];
                s_acc[ni] = __builtin_amdgcn_mfma_f32_16x16x32_f16(aq[kc], bk, s_acc[ni], 0, 0, 0);
            }
        __syncthreads();   // all waves done reading K before P overwrite

        float rb[8];
#pragma unroll
        for (int ni = 0; ni < 8; ++ni) {
            int j = j0 + ni * 16 + ccol;
            rb[ni] = (j < Qc - 1) ? r_bias[(j + 1) * Nh + n] : 0.0f;
        }

        // online softmax per owned row (wave-local), write P to sKP
#pragma unroll
        for (int r = 0; r < 4; ++r) {
            float vv[8], mx = -1e30f;
#pragma unroll
            for (int ni = 0; ni < 8; ++ni) {
                vv[ni] = (s_acc[ni][r] + rb[ni]) * ATT_SCALE;
                mx = fmaxf(mx, vv[ni]);
            }
#pragma unroll
            for (int msk = 1; msk < 16; msk <<= 1) mx = fmaxf(mx, __shfl_xor(mx, msk));
            float mn = fmaxf(m_i[r], mx);
            float alpha = __expf(m_i[r] - mn);
            float sm = 0.0f;
#pragma unroll
            for (int ni = 0; ni < 8; ++ni) { vv[ni] = __expf(vv[ni] - mn); sm += vv[ni]; }
#pragma unroll
            for (int msk = 1; msk < 16; msk <<= 1) sm += __shfl_xor(sm, msk);
            l_i[r] = l_i[r] * alpha + sm;
            m_i[r] = mn;
#pragma unroll
            for (int ni = 0; ni < 4; ++ni) o_acc[ni][r] *= alpha;
            int prow = wave * 16 + crow + r;
#pragma unroll
            for (int ni = 0; ni < 8; ++ni)
                sKP[prow * LDL + ni * 16 + ccol] = (f16)vv[ni];
        }
        // no barrier: each wave reads only its own P rows (lgkmcnt ordering)

        // PV: A = P (own 16 rows, k=128), B = V^T (64 d-rows, k=j)
#pragma unroll
        for (int kc = 0; kc < 4; ++kc) {
            f16x8 ap = *(const f16x8*)&sKP[(wave * 16 + lrow) * LDL + kc * 32 + kq];
#pragma unroll
            for (int ni = 0; ni < 4; ++ni) {
                f16x8 bv = *(const f16x8*)&sV[(ni * 16 + lrow) * LDL + kc * 32 + kq];
                o_acc[ni] = __builtin_amdgcn_mfma_f32_16x16x32_f16(ap, bv, o_acc[ni], 0, 0, 0);
            }
        }
    }

    // epilogue: avp[b][i][n*64+d] = O / l
#pragma unroll
    for (int r = 0; r < 4; ++r) {
        int i = i0 + wave * 16 + crow + r;
        float inv = 1.0f / l_i[r];
#pragma unroll
        for (int ni = 0; ni < 4; ++ni) {
            int d = ni * 16 + ccol;
            avp[((long)(b * Qc + i) << 10) + n * 64 + d] = (f16)(o_acc[ni][r] * inv);
        }
    }
}

// ---------------- residual + LayerNorm (f32 inputs, f32 output) ----------------
__global__ __launch_bounds__(256) void k_res_ln(const float* __restrict__ w, const float* __restrict__ ao,
                                                const float* __restrict__ gamma, const float* __restrict__ beta,
                                                float* __restrict__ out) {
    const long base = (long)blockIdx.x * 1024;
    const int tid = threadIdx.x;
    float x[4], s = 0.0f, s2 = 0.0f;
#pragma unroll
    for (int k = 0; k < 4; ++k) {
        int j = tid + k * 256;
        x[k] = w[base + j] + ao[base + j];
        s += x[k];
        s2 += x[k] * x[k];
    }
#pragma unroll
    for (int off = 32; off; off >>= 1) { s += __shfl_down(s, off); s2 += __shfl_down(s2, off); }
    __shared__ float rs[4], rs2[4];
    if ((tid & 63) == 0) { rs[tid >> 6] = s; rs2[tid >> 6] = s2; }
    __syncthreads();
    s = rs[0] + rs[1] + rs[2] + rs[3];
    s2 = rs2[0] + rs2[1] + rs2[2] + rs2[3];
    float mu = s * (1.0f / 1024.0f);
    float var = s2 * (1.0f / 1024.0f) - mu * mu;
    float inv = rsqrtf(var + 1e-5f);
#pragma unroll
    for (int k = 0; k < 4; ++k) {
        int j = tid + k * 256;
        out[base + j] = (x[k] - mu) * inv * gamma[j] + beta[j];
    }
}

extern "C" void kernel_launch(void* const* d_in, const int* in_sizes, int n_in,
                              void* d_out, int out_size, void* d_ws, size_t ws_size,
                              hipStream_t stream) {
    const float* w_in   = (const float*)d_in[0];
    const float* r_emb  = (const float*)d_in[1];
    const float* r_wb   = (const float*)d_in[2];
    const float* r_bias = (const float*)d_in[3];
    const float* Wq     = (const float*)d_in[4];
    const float* Wk     = (const float*)d_in[5];
    const float* Wv     = (const float*)d_in[6];
    const float* Wo     = (const float*)d_in[7];
    const float* ln_g   = (const float*)d_in[8];
    const float* ln_b   = (const float*)d_in[9];
    float* out = (float*)d_out;

    // workspace carve-out (fixed 80MB)
    char* p = (char*)d_ws;
    auto alloc = [&](size_t bytes) { char* r = p; p += (bytes + 255) & ~(size_t)255; return r; };
    f16*   wh  = (f16*)alloc((size_t)BQ * Dc * 2);          // 8 MB
    f16*   WT  = (f16*)alloc((size_t)4 * Dc * Dc * 2);      // 8 MB: WqT,WkT,WvT,WoT
    f16*   qh  = (f16*)alloc((size_t)BQ * Dc * 2);          // 8 MB
    f16*   kh  = (f16*)alloc((size_t)BQ * Dc * 2);
    f16*   vh  = (f16*)alloc((size_t)BQ * Dc * 2);
    f16*   vT  = (f16*)alloc((size_t)BQ * Dc * 2);          // [b][dcol][i]
    f16*   Qt  = (f16*)alloc((size_t)NHEAD * Qc * 128 * 2); // 16 MB
    f16*   Kt  = (f16*)alloc((size_t)NHEAD * Qc * 128 * 2); // 16 MB
    f16*   WqT = WT, *WkT = WT + (size_t)Dc * Dc, *WvT = WT + (size_t)2 * Dc * Dc,
         *WoT = WT + (size_t)3 * Dc * Dc;
    // aliases (liveness-checked): kh dead after build_qtkt; Qt dead after flash
    f16*   avp = kh;                 // [b][i][1024] f16
    float* ao  = (float*)Qt;         // 16 MB fp32

    // 1. f32->f16 of w (8/thread)
    k_f2h<<<(BQ * Dc) / (256 * 8), 256, 0, stream>>>(w_in, wh);

    // 2. transpose 4 weights in one dispatch (f32 -> f16)
    Ptr4 srcs{{Wq, Wk, Wv, Wo}};
    k_transpose4<<<dim3(32, 32, 4), dim3(32, 8), 0, stream>>>(srcs, WT);

    // 3. projections: qh/kh/vh = wh @ W*^T
    k_gemm_nt<128, 128, 32, 2, 2, false><<<dim3(Dc / 128, BQ / 128, 1), 256, 0, stream>>>(
        wh, WqT, qh, BQ, Dc, Dc, Dc, Dc, Dc, 0, 0, 0);
    k_gemm_nt<128, 128, 32, 2, 2, false><<<dim3(Dc / 128, BQ / 128, 1), 256, 0, stream>>>(
        wh, WkT, kh, BQ, Dc, Dc, Dc, Dc, Dc, 0, 0, 0);
    k_gemm_nt<128, 128, 32, 2, 2, false><<<dim3(Dc / 128, BQ / 128, 1), 256, 0, stream>>>(
        wh, WvT, vh, BQ, Dc, Dc, Dc, Dc, Dc, 0, 0, 0);

    // 4. concatenated Q~/K~ with rel-shift folded into K~ (8/thread)
    k_build_qtkt<<<(NHEAD * Qc * 16) / 256, 256, 0, stream>>>(qh, kh, r_wb, r_emb, Qt, Kt);

    // 5. vT: per-b transpose of vh -> [b][dcol][i]
    k_transpose_h<<<dim3(32, 32, Bc), dim3(32, 8), 0, stream>>>(vh, vT, Qc, Dc,
                                                                (long)Qc * Dc, (long)Qc * Dc);

    // 6. fused attention: S -> online softmax(+r_bias shift) -> PV, writes avp
    k_flash<<<dim3(Qc / 64, NHEAD), 256, 0, stream>>>(Qt, Kt, vT, r_bias, avp);

    // 7. attn_out = avp @ Wo^T (fp32 out, into aliased ao)
    k_gemm_nt<128, 128, 32, 2, 2, true><<<dim3(Dc / 128, BQ / 128, 1), 256, 0, stream>>>(
        avp, WoT, ao, BQ, Dc, Dc, Dc, Dc, Dc, 0, 0, 0);

    // 8. out = LayerNorm(w + attn_out), fp32 output
    k_res_ln<<<BQ, 256, 0, stream>>>(w_in, ao, ln_g, ln_b, out);
}

// Round 7
// 291.289 us; speedup vs baseline: 2.2277x; 1.1484x over previous
//
#include <hip/hip_runtime.h>
#include <hip/hip_bf16.h>

using f16 = _Float16;
typedef _Float16 f16x8 __attribute__((ext_vector_type(8)));
typedef float f32x4 __attribute__((ext_vector_type(4)));

#define AS1 __attribute__((address_space(1)))
#define AS3 __attribute__((address_space(3)))

// Problem constants
constexpr int Bc = 4, Qc = 1024, Dc = 1024, Nh = 16, DHc = 64;
constexpr int BQ = Bc * Qc;      // 4096 rows of w
constexpr int NHEAD = Bc * Nh;   // 64 (b,n) heads
constexpr float ATT_SCALE = 0.125f;

// ---------------- f32 -> f16, 8 elems/thread ----------------
__global__ void k_f2h(const float* __restrict__ src, f16* __restrict__ dst) {
    long i8 = ((long)blockIdx.x * blockDim.x + threadIdx.x) * 8;
    float4 a = *(const float4*)&src[i8];
    float4 b = *(const float4*)&src[i8 + 4];
    f16x8 o = { (f16)a.x, (f16)a.y, (f16)a.z, (f16)a.w,
                (f16)b.x, (f16)b.y, (f16)b.z, (f16)b.w };
    *(f16x8*)&dst[i8] = o;
}

// ---------------- merged 4-way weight transpose: src[z][R][C] -> dst[z][C][R] f16 ----------------
struct Ptr4 { const float* p[4]; };
__global__ void k_transpose4(Ptr4 srcs, f16* __restrict__ dst) {
    __shared__ f16 tile[32][33];
    const float* src = srcs.p[blockIdx.z];
    f16* d = dst + (long)blockIdx.z * Dc * Dc;
    int c0 = blockIdx.x * 32, r0 = blockIdx.y * 32;
#pragma unroll
    for (int dy = 0; dy < 32; dy += 8) {
        int r = r0 + threadIdx.y + dy, c = c0 + threadIdx.x;
        tile[threadIdx.y + dy][threadIdx.x] = (f16)src[(long)r * Dc + c];
    }
    __syncthreads();
#pragma unroll
    for (int dy = 0; dy < 32; dy += 8) {
        int c = c0 + threadIdx.y + dy, r = r0 + threadIdx.x;
        d[(long)c * Dc + r] = tile[threadIdx.x][threadIdx.y + dy];
    }
}

// ---------------- fill Kt[h][j][64:128] = r_emb[j+1][n][:] (0 at j=1023) ----------------
__global__ void k_fill_remb(const float* __restrict__ remb, f16* __restrict__ Kt) {
    long gid = (long)blockIdx.x * blockDim.x + threadIdx.x;  // 64*1024*8
    int d8 = (int)(gid & 7) * 8;
    int j = (int)((gid >> 3) & 1023);
    int h = (int)(gid >> 13);
    int n = h & 15;
    f16x8 kv;
    if (j < 1023) {
        const float* rp = &remb[((long)(j + 1) * 16 + n) * 64 + d8];
        float4 r0 = *(const float4*)rp, r1 = *(const float4*)(rp + 4);
        kv[0] = (f16)r0.x; kv[1] = (f16)r0.y; kv[2] = (f16)r0.z; kv[3] = (f16)r0.w;
        kv[4] = (f16)r1.x; kv[5] = (f16)r1.y; kv[6] = (f16)r1.z; kv[7] = (f16)r1.w;
    } else {
        kv = f16x8{};
    }
    *(f16x8*)&Kt[(((long)h << 10) + j) * 128 + 64 + d8] = kv;
}

// ---------------- NT GEMM, global_load_lds staging, fused epilogues ----------------
// EPI: 0 = f16 row-major; 1 = f32 row-major; 2 = Qt dual-write (+r_w_bias via aux);
//      3 = Kt first-half;  4 = vT transposed store.
template <int BM, int BN, int BK, int WROWS, int WCOLS, int EPI>
__global__ __launch_bounds__(256) void k_gemm_nt(
    const f16* __restrict__ A, const f16* __restrict__ Bt, void* __restrict__ Cv,
    const float* __restrict__ aux, int lda, int ldb, int ldc, int K)
{
    constexpr int TM = BM / (WROWS * 16);
    constexpr int TN = BN / (WCOLS * 16);
    __shared__ __align__(16) f16 sA[BM * BK];
    __shared__ __align__(16) f16 sB[BN * BK];

    const int tid = threadIdx.x;
    const int lane = tid & 63, wave = tid >> 6;
    const int wm = wave / WCOLS, wn = wave % WCOLS;
    const int m0 = blockIdx.y * BM, n0 = blockIdx.x * BN;

    f32x4 acc[TM][TN] = {};

    const int lrow = lane & 15;
    const int kq = (lane >> 4) * 8;
    const int srow = lane >> 2;            // 16 rows per 1KB chunk
    const int scol = (lane & 3) * 8;       // 4 lanes x 8 f16 per 64B row

    for (int k0 = 0; k0 < K; k0 += BK) {
        __syncthreads();
        constexpr int CHA = BM * BK / 512;   // 1KB chunks
#pragma unroll
        for (int ch = 0; ch < CHA / 4; ++ch) {
            int cc = ch * 4 + wave;
            __builtin_amdgcn_global_load_lds(
                (const AS1 void*)(const void*)&A[(long)(m0 + cc * 16 + srow) * lda + k0 + scol],
                (AS3 void*)(void*)&sA[cc * 512], 16, 0, 0);
        }
        constexpr int CHB = BN * BK / 512;
#pragma unroll
        for (int ch = 0; ch < CHB / 4; ++ch) {
            int cc = ch * 4 + wave;
            __builtin_amdgcn_global_load_lds(
                (const AS1 void*)(const void*)&Bt[(long)(n0 + cc * 16 + srow) * ldb + k0 + scol],
                (AS3 void*)(void*)&sB[cc * 512], 16, 0, 0);
        }
        __syncthreads();

        f16x8 af[TM], bfr[TN];
#pragma unroll
        for (int mi = 0; mi < TM; ++mi)
            af[mi] = *(const f16x8*)&sA[(wm * TM * 16 + mi * 16 + lrow) * BK + kq];
#pragma unroll
        for (int ni = 0; ni < TN; ++ni)
            bfr[ni] = *(const f16x8*)&sB[(wn * TN * 16 + ni * 16 + lrow) * BK + kq];
#pragma unroll
        for (int mi = 0; mi < TM; ++mi)
#pragma unroll
            for (int ni = 0; ni < TN; ++ni)
                acc[mi][ni] = __builtin_amdgcn_mfma_f32_16x16x32_f16(af[mi], bfr[ni], acc[mi][ni], 0, 0, 0);
    }

    const int crow = (lane >> 4) * 4;
    const int ccol = lane & 15;
#pragma unroll
    for (int mi = 0; mi < TM; ++mi)
#pragma unroll
        for (int ni = 0; ni < TN; ++ni)
#pragma unroll
            for (int r = 0; r < 4; ++r) {
                int gm = m0 + wm * TM * 16 + mi * 16 + crow + r;
                int gn = n0 + wn * TN * 16 + ni * 16 + ccol;
                float val = acc[mi][ni][r];
                if constexpr (EPI == 0) {
                    ((f16*)Cv)[(long)gm * ldc + gn] = (f16)val;
                } else if constexpr (EPI == 1) {
                    ((float*)Cv)[(long)gm * ldc + gn] = val;
                } else if constexpr (EPI == 2) {
                    // Qt[h=(b*16+n)][i][d] = val + rwb; [64+d] = val
                    int n = gn >> 6, d = gn & 63, b = gm >> 10, i = gm & 1023;
                    long rowbase = ((((long)((b << 4) + n) << 10) + i) << 7);
                    ((f16*)Cv)[rowbase + d] = (f16)(val + aux[gn]);
                    ((f16*)Cv)[rowbase + 64 + d] = (f16)val;
                } else if constexpr (EPI == 3) {
                    // Kt[h][j][d] = val (second half filled by k_fill_remb)
                    int n = gn >> 6, d = gn & 63, b = gm >> 10, j = gm & 1023;
                    long rowbase = ((((long)((b << 4) + n) << 10) + j) << 7);
                    ((f16*)Cv)[rowbase + d] = (f16)val;
                } else {
                    // vT[b][gn][i] = val  (transposed store)
                    int b = gm >> 10, i = gm & 1023;
                    ((f16*)Cv)[(((long)(b << 10) + gn) << 10) + i] = (f16)val;
                }
            }
}

// ---------------- fused flash attention, TM=2 (32 rows/wave) ----------------
// Block: 1 head, 128 Q-rows; wave w owns rows [w*32, w*32+32) so online-softmax
// state is wave-local. Q frags in registers. sKP: K-tile then P-tile (128x136).
// P write->read wave-local (no barrier). launch_bounds(256,2): VGPR cap 256 —
// the ~180-reg live set MUST NOT spill (round-5 lesson: (256,3) cap 170 spilled,
// WRITE_SIZE 8->120MB).
__global__ __launch_bounds__(256, 2) void k_flash(
    const f16* __restrict__ Qt, const f16* __restrict__ Kt,
    const f16* __restrict__ vT, const float* __restrict__ r_bias,
    f16* __restrict__ avp)
{
    constexpr int LDL = 136;
    __shared__ __align__(16) f16 sKP[128 * LDL];   // K-tile, then P-tile
    __shared__ __align__(16) f16 sV[64 * LDL];

    const int tid = threadIdx.x, lane = tid & 63, wave = tid >> 6;
    const int i0 = blockIdx.x * 128;
    const int h = blockIdx.y;
    const int b = h >> 4, n = h & 15;

    const f16* Qh = Qt + (long)h * Qc * 128;
    const f16* Kh = Kt + (long)h * Qc * 128;
    const f16* Vh = vT + (long)h * DHc * Qc;

    const int lrow = lane & 15, kq = (lane >> 4) * 8;
    const int crow = (lane >> 4) * 4, ccol = lane & 15;

    // Q fragments in registers: rows i0 + wave*32 + t*16 + lrow
    f16x8 aq[2][4];
#pragma unroll
    for (int t = 0; t < 2; ++t)
#pragma unroll
        for (int kc = 0; kc < 4; ++kc)
            aq[t][kc] = *(const f16x8*)&Qh[(long)(i0 + wave * 32 + t * 16 + lrow) * 128 + kc * 32 + kq];

    float m_i[2][4], l_i[2][4];
#pragma unroll
    for (int t = 0; t < 2; ++t)
#pragma unroll
        for (int r = 0; r < 4; ++r) { m_i[t][r] = -1e30f; l_i[t][r] = 0.0f; }
    f32x4 o_acc[2][4] = {};   // per wave: 32 rows x 64 d-cols

    for (int j0 = 0; j0 < Qc; j0 += 128) {
        __syncthreads();   // prev iter's P/V reads complete before restage
        for (int idx = tid; idx < 128 * 16; idx += 256) {
            int r = idx >> 4, c = (idx & 15) * 8;
            *(uint4*)&sKP[r * LDL + c] = *(const uint4*)&Kh[(long)(j0 + r) * 128 + c];
        }
        for (int idx = tid; idx < 64 * 16; idx += 256) {
            int r = idx >> 4, c = (idx & 15) * 8;
            *(uint4*)&sV[r * LDL + c] = *(const uint4*)&Vh[(long)r * Qc + j0 + c];
        }
        __syncthreads();

        // S-tile: 32 rows (2 tiles) x 128 cols, K-depth 128; bk shared by both row-tiles
        f32x4 s_acc[2][8] = {};
#pragma unroll
        for (int kc = 0; kc < 4; ++kc)
#pragma unroll
            for (int ni = 0; ni < 8; ++ni) {
                f16x8 bk = *(const f16x8*)&sKP[(ni * 16 + lrow) * LDL + kc * 32 + kq];
                s_acc[0][ni] = __builtin_amdgcn_mfma_f32_16x16x32_f16(aq[0][kc], bk, s_acc[0][ni], 0, 0, 0);
                s_acc[1][ni] = __builtin_amdgcn_mfma_f32_16x16x32_f16(aq[1][kc], bk, s_acc[1][ni], 0, 0, 0);
            }
        __syncthreads();   // all waves done reading K before P overwrite

        float rb[8];
#pragma unroll
        for (int ni = 0; ni < 8; ++ni) {
            int j = j0 + ni * 16 + ccol;
            rb[ni] = (j < Qc - 1) ? r_bias[(j + 1) * Nh + n] : 0.0f;
        }

        // online softmax per owned row (wave-local), write P to sKP
#pragma unroll
        for (int t = 0; t < 2; ++t)
#pragma unroll
            for (int r = 0; r < 4; ++r) {
                float vv[8], mx = -1e30f;
#pragma unroll
                for (int ni = 0; ni < 8; ++ni) {
                    vv[ni] = (s_acc[t][ni][r] + rb[ni]) * ATT_SCALE;
                    mx = fmaxf(mx, vv[ni]);
                }
#pragma unroll
                for (int msk = 1; msk < 16; msk <<= 1) mx = fmaxf(mx, __shfl_xor(mx, msk));
                float mn = fmaxf(m_i[t][r], mx);
                float alpha = __expf(m_i[t][r] - mn);
                float sm = 0.0f;
#pragma unroll
                for (int ni = 0; ni < 8; ++ni) { vv[ni] = __expf(vv[ni] - mn); sm += vv[ni]; }
#pragma unroll
                for (int msk = 1; msk < 16; msk <<= 1) sm += __shfl_xor(sm, msk);
                l_i[t][r] = l_i[t][r] * alpha + sm;
                m_i[t][r] = mn;
#pragma unroll
                for (int ni = 0; ni < 4; ++ni) o_acc[t][ni][r] *= alpha;
                int prow = wave * 32 + t * 16 + crow + r;
#pragma unroll
                for (int ni = 0; ni < 8; ++ni)
                    sKP[prow * LDL + ni * 16 + ccol] = (f16)vv[ni];
            }
        // no barrier: each wave reads only its own P rows (lgkmcnt ordering)

        // PV: A = P (own 32 rows, k=128), B = V^T (64 d-rows, k=j)
#pragma unroll
        for (int kc = 0; kc < 4; ++kc) {
            f16x8 ap0 = *(const f16x8*)&sKP[(wave * 32 + lrow) * LDL + kc * 32 + kq];
            f16x8 ap1 = *(const f16x8*)&sKP[(wave * 32 + 16 + lrow) * LDL + kc * 32 + kq];
#pragma unroll
            for (int ni = 0; ni < 4; ++ni) {
                f16x8 bv = *(const f16x8*)&sV[(ni * 16 + lrow) * LDL + kc * 32 + kq];
                o_acc[0][ni] = __builtin_amdgcn_mfma_f32_16x16x32_f16(ap0, bv, o_acc[0][ni], 0, 0, 0);
                o_acc[1][ni] = __builtin_amdgcn_mfma_f32_16x16x32_f16(ap1, bv, o_acc[1][ni], 0, 0, 0);
            }
        }
    }

    // epilogue: avp[b][i][n*64+d] = O / l
#pragma unroll
    for (int t = 0; t < 2; ++t)
#pragma unroll
        for (int r = 0; r < 4; ++r) {
            int i = i0 + wave * 32 + t * 16 + crow + r;
            float inv = 1.0f / l_i[t][r];
#pragma unroll
            for (int ni = 0; ni < 4; ++ni) {
                int d = ni * 16 + ccol;
                avp[((long)(b * Qc + i) << 10) + n * 64 + d] = (f16)(o_acc[t][ni][r] * inv);
            }
        }
}

// ---------------- residual + LayerNorm (f32 inputs, f32 output) ----------------
__global__ __launch_bounds__(256) void k_res_ln(const float* __restrict__ w, const float* __restrict__ ao,
                                                const float* __restrict__ gamma, const float* __restrict__ beta,
                                                float* __restrict__ out) {
    const long base = (long)blockIdx.x * 1024;
    const int tid = threadIdx.x;
    float x[4], s = 0.0f, s2 = 0.0f;
#pragma unroll
    for (int k = 0; k < 4; ++k) {
        int j = tid + k * 256;
        x[k] = w[base + j] + ao[base + j];
        s += x[k];
        s2 += x[k] * x[k];
    }
#pragma unroll
    for (int off = 32; off; off >>= 1) { s += __shfl_down(s, off); s2 += __shfl_down(s2, off); }
    __shared__ float rs[4], rs2[4];
    if ((tid & 63) == 0) { rs[tid >> 6] = s; rs2[tid >> 6] = s2; }
    __syncthreads();
    s = rs[0] + rs[1] + rs[2] + rs[3];
    s2 = rs2[0] + rs2[1] + rs2[2] + rs2[3];
    float mu = s * (1.0f / 1024.0f);
    float var = s2 * (1.0f / 1024.0f) - mu * mu;
    float inv = rsqrtf(var + 1e-5f);
#pragma unroll
    for (int k = 0; k < 4; ++k) {
        int j = tid + k * 256;
        out[base + j] = (x[k] - mu) * inv * gamma[j] + beta[j];
    }
}

extern "C" void kernel_launch(void* const* d_in, const int* in_sizes, int n_in,
                              void* d_out, int out_size, void* d_ws, size_t ws_size,
                              hipStream_t stream) {
    const float* w_in   = (const float*)d_in[0];
    const float* r_emb  = (const float*)d_in[1];
    const float* r_wb   = (const float*)d_in[2];
    const float* r_bias = (const float*)d_in[3];
    const float* Wq     = (const float*)d_in[4];
    const float* Wk     = (const float*)d_in[5];
    const float* Wv     = (const float*)d_in[6];
    const float* Wo     = (const float*)d_in[7];
    const float* ln_g   = (const float*)d_in[8];
    const float* ln_b   = (const float*)d_in[9];
    float* out = (float*)d_out;

    // workspace carve-out (56MB fixed + aliases)
    char* p = (char*)d_ws;
    auto alloc = [&](size_t bytes) { char* r = p; p += (bytes + 255) & ~(size_t)255; return r; };
    f16* wh = (f16*)alloc((size_t)BQ * Dc * 2);          // 8 MB
    f16* WT = (f16*)alloc((size_t)4 * Dc * Dc * 2);      // 8 MB: WqT,WkT,WvT,WoT
    f16* Qt = (f16*)alloc((size_t)NHEAD * Qc * 128 * 2); // 16 MB
    f16* Kt = (f16*)alloc((size_t)NHEAD * Qc * 128 * 2); // 16 MB
    f16* vT = (f16*)alloc((size_t)BQ * Dc * 2);          // 8 MB [b][dcol][i]
    f16* WqT = WT, *WkT = WT + (size_t)Dc * Dc, *WvT = WT + (size_t)2 * Dc * Dc,
       *WoT = WT + (size_t)3 * Dc * Dc;
    // aliases (liveness-checked): wh dead after the 3 proj GEMMs; Qt dead after flash
    f16*   avp = wh;                 // [b][i][1024] f16
    float* ao  = (float*)Qt;         // 16 MB fp32

    // 1. f32->f16 of w (8/thread)
    k_f2h<<<(BQ * Dc) / (256 * 8), 256, 0, stream>>>(w_in, wh);

    // 2. transpose 4 weights in one dispatch (f32 -> f16)
    Ptr4 srcs{{Wq, Wk, Wv, Wo}};
    k_transpose4<<<dim3(32, 32, 4), dim3(32, 8), 0, stream>>>(srcs, WT);

    // 3. rel-shifted r_emb -> Kt[...][64:128] (independent of GEMMs)
    k_fill_remb<<<(NHEAD * Qc * 8) / 256, 256, 0, stream>>>(r_emb, Kt);

    // 4. projections with fused epilogues
    k_gemm_nt<128, 128, 32, 2, 2, 2><<<dim3(Dc / 128, BQ / 128), 256, 0, stream>>>(
        wh, WqT, Qt, r_wb, Dc, Dc, 0, Dc);
    k_gemm_nt<128, 128, 32, 2, 2, 3><<<dim3(Dc / 128, BQ / 128), 256, 0, stream>>>(
        wh, WkT, Kt, nullptr, Dc, Dc, 0, Dc);
    k_gemm_nt<128, 128, 32, 2, 2, 4><<<dim3(Dc / 128, BQ / 128), 256, 0, stream>>>(
        wh, WvT, vT, nullptr, Dc, Dc, 0, Dc);

    // 5. fused attention: S -> online softmax(+r_bias shift) -> PV, writes avp
    k_flash<<<dim3(Qc / 128, NHEAD), 256, 0, stream>>>(Qt, Kt, vT, r_bias, avp);

    // 6. attn_out = avp @ Wo^T (fp32 out, into aliased ao)
    k_gemm_nt<128, 128, 32, 2, 2, 1><<<dim3(Dc / 128, BQ / 128), 256, 0, stream>>>(
        avp, WoT, ao, nullptr, Dc, Dc, Dc, Dc);

    // 7. out = LayerNorm(w + attn_out), fp32 output
    k_res_ln<<<BQ, 256, 0, stream>>>(w_in, ao, ln_g, ln_b, out);
}

// Round 8
// 241.358 us; speedup vs baseline: 2.6886x; 1.2069x over previous
//
#include <hip/hip_runtime.h>
#include <hip/hip_bf16.h>

using f16 = _Float16;
typedef _Float16 f16x8 __attribute__((ext_vector_type(8)));
typedef _Float16 f16x4 __attribute__((ext_vector_type(4)));
typedef float f32x4 __attribute__((ext_vector_type(4)));

#define AS1 __attribute__((address_space(1)))
#define AS3 __attribute__((address_space(3)))

// Problem constants
constexpr int Bc = 4, Qc = 1024, Dc = 1024, Nh = 16, DHc = 64;
constexpr int BQ = Bc * Qc;      // 4096 rows of w
constexpr int NHEAD = Bc * Nh;   // 64 (b,n) heads
constexpr float ATT_SCALE = 0.125f;

// ---------------- f32 -> f16, 8 elems/thread ----------------
__global__ void k_f2h(const float* __restrict__ src, f16* __restrict__ dst) {
    long i8 = ((long)blockIdx.x * blockDim.x + threadIdx.x) * 8;
    float4 a = *(const float4*)&src[i8];
    float4 b = *(const float4*)&src[i8 + 4];
    f16x8 o = { (f16)a.x, (f16)a.y, (f16)a.z, (f16)a.w,
                (f16)b.x, (f16)b.y, (f16)b.z, (f16)b.w };
    *(f16x8*)&dst[i8] = o;
}

// ---------------- merged 4-way weight transpose: src[z][R][C] -> dst[z][C][R] f16 ----------------
struct Ptr4 { const float* p[4]; };
__global__ void k_transpose4(Ptr4 srcs, f16* __restrict__ dst) {
    __shared__ f16 tile[32][33];
    const float* src = srcs.p[blockIdx.z];
    f16* d = dst + (long)blockIdx.z * Dc * Dc;
    int c0 = blockIdx.x * 32, r0 = blockIdx.y * 32;
#pragma unroll
    for (int dy = 0; dy < 32; dy += 8) {
        int r = r0 + threadIdx.y + dy, c = c0 + threadIdx.x;
        tile[threadIdx.y + dy][threadIdx.x] = (f16)src[(long)r * Dc + c];
    }
    __syncthreads();
#pragma unroll
    for (int dy = 0; dy < 32; dy += 8) {
        int c = c0 + threadIdx.y + dy, r = r0 + threadIdx.x;
        d[(long)c * Dc + r] = tile[threadIdx.x][threadIdx.y + dy];
    }
}

// ---------------- fill Kt[h][j][64:128] = r_emb[j+1][n][:] (0 at j=1023) ----------------
__global__ void k_fill_remb(const float* __restrict__ remb, f16* __restrict__ Kt) {
    long gid = (long)blockIdx.x * blockDim.x + threadIdx.x;  // 64*1024*8
    int d8 = (int)(gid & 7) * 8;
    int j = (int)((gid >> 3) & 1023);
    int h = (int)(gid >> 13);
    int n = h & 15;
    f16x8 kv;
    if (j < 1023) {
        const float* rp = &remb[((long)(j + 1) * 16 + n) * 64 + d8];
        float4 r0 = *(const float4*)rp, r1 = *(const float4*)(rp + 4);
        kv[0] = (f16)r0.x; kv[1] = (f16)r0.y; kv[2] = (f16)r0.z; kv[3] = (f16)r0.w;
        kv[4] = (f16)r1.x; kv[5] = (f16)r1.y; kv[6] = (f16)r1.z; kv[7] = (f16)r1.w;
    } else {
        kv = f16x8{};
    }
    *(f16x8*)&Kt[(((long)h << 10) + j) * 128 + 64 + d8] = kv;
}

// ---------------- NT GEMM, global_load_lds staging, fused epilogues ----------------
// EPI: 1 = f32 row-major (Cv); 5 = fused QKV scatter (qtp/ktp/vtp, segment by n0>>10).
template <int BM, int BN, int BK, int WROWS, int WCOLS, int EPI>
__global__ __launch_bounds__(256) void k_gemm_nt(
    const f16* __restrict__ A, const f16* __restrict__ Bt, void* __restrict__ Cv,
    const float* __restrict__ aux, f16* __restrict__ qtp, f16* __restrict__ ktp,
    f16* __restrict__ vtp, int lda, int ldb, int ldc, int K)
{
    constexpr int TM = BM / (WROWS * 16);
    constexpr int TN = BN / (WCOLS * 16);
    __shared__ __align__(16) f16 sA[BM * BK];
    __shared__ __align__(16) f16 sB[BN * BK];

    const int tid = threadIdx.x;
    const int lane = tid & 63, wave = tid >> 6;
    const int wm = wave / WCOLS, wn = wave % WCOLS;
    const int m0 = blockIdx.y * BM, n0 = blockIdx.x * BN;

    f32x4 acc[TM][TN] = {};

    const int lrow = lane & 15;
    const int kq = (lane >> 4) * 8;
    const int srow = lane >> 2;            // 16 rows per 1KB chunk
    const int scol = (lane & 3) * 8;       // 4 lanes x 8 f16 per 64B row

    for (int k0 = 0; k0 < K; k0 += BK) {
        __syncthreads();
        constexpr int CHA = BM * BK / 512;   // 1KB chunks
#pragma unroll
        for (int ch = 0; ch < CHA / 4; ++ch) {
            int cc = ch * 4 + wave;
            __builtin_amdgcn_global_load_lds(
                (const AS1 void*)(const void*)&A[(long)(m0 + cc * 16 + srow) * lda + k0 + scol],
                (AS3 void*)(void*)&sA[cc * 512], 16, 0, 0);
        }
        constexpr int CHB = BN * BK / 512;
#pragma unroll
        for (int ch = 0; ch < CHB / 4; ++ch) {
            int cc = ch * 4 + wave;
            __builtin_amdgcn_global_load_lds(
                (const AS1 void*)(const void*)&Bt[(long)(n0 + cc * 16 + srow) * ldb + k0 + scol],
                (AS3 void*)(void*)&sB[cc * 512], 16, 0, 0);
        }
        __syncthreads();

        f16x8 af[TM], bfr[TN];
#pragma unroll
        for (int mi = 0; mi < TM; ++mi)
            af[mi] = *(const f16x8*)&sA[(wm * TM * 16 + mi * 16 + lrow) * BK + kq];
#pragma unroll
        for (int ni = 0; ni < TN; ++ni)
            bfr[ni] = *(const f16x8*)&sB[(wn * TN * 16 + ni * 16 + lrow) * BK + kq];
#pragma unroll
        for (int mi = 0; mi < TM; ++mi)
#pragma unroll
            for (int ni = 0; ni < TN; ++ni)
                acc[mi][ni] = __builtin_amdgcn_mfma_f32_16x16x32_f16(af[mi], bfr[ni], acc[mi][ni], 0, 0, 0);
    }

    const int crow = (lane >> 4) * 4;
    const int ccol = lane & 15;
#pragma unroll
    for (int mi = 0; mi < TM; ++mi)
#pragma unroll
        for (int ni = 0; ni < TN; ++ni)
#pragma unroll
            for (int r = 0; r < 4; ++r) {
                int gm = m0 + wm * TM * 16 + mi * 16 + crow + r;
                int gn = n0 + wn * TN * 16 + ni * 16 + ccol;
                float val = acc[mi][ni][r];
                if constexpr (EPI == 1) {
                    ((float*)Cv)[(long)gm * ldc + gn] = val;
                } else {
                    // fused QKV scatter; segment uniform per block (BN=128 | 1024)
                    int seg = n0 >> 10;
                    int col = gn & 1023;
                    int n = col >> 6, d = col & 63, b = gm >> 10, i = gm & 1023;
                    long rowbase = ((((long)((b << 4) + n) << 10) + i) << 7);
                    if (seg == 0) {
                        qtp[rowbase + d] = (f16)(val + aux[col]);
                        qtp[rowbase + 64 + d] = (f16)val;
                    } else if (seg == 1) {
                        ktp[rowbase + d] = (f16)val;
                    } else {
                        vtp[(((long)(b << 10) + col) << 10) + i] = (f16)val;
                    }
                }
            }
}

// ---------------- fused flash attention v3: S^T layout, P in registers ----------------
// Block: 1 head, 128 Q-rows; wave w owns q in [w*32, w*32+32) (2 tiles of 16).
// S^T = mfma(K-frag, Q-frag): D[m=j][n=q] -> lane holds q=lane&15, j=quad*4+reg.
// exp(S^T) rows-of-4-j per lane == A-frag of mfma_f32_16x16x16f16 -> PV with no
// LDS round-trip for P. launch_bounds(256,2): VGPR cap 256, must not spill
// (tripwire: flash WRITE_SIZE must stay 8192 KB).
__global__ __launch_bounds__(256, 2) void k_flash(
    const f16* __restrict__ Qt, const f16* __restrict__ Kt,
    const f16* __restrict__ vT, const float* __restrict__ r_bias,
    f16* __restrict__ avp)
{
    constexpr int LDL = 136;
    __shared__ __align__(16) f16 sK[128 * LDL];
    __shared__ __align__(16) f16 sV[64 * LDL];
    __shared__ float sRB[128];

    const int tid = threadIdx.x, lane = tid & 63, wave = tid >> 6;
    const int i0 = blockIdx.x * 128;
    const int h = blockIdx.y;
    const int b = h >> 4, n = h & 15;

    const f16* Qh = Qt + (long)h * Qc * 128;
    const f16* Kh = Kt + (long)h * Qc * 128;
    const f16* Vh = vT + (long)h * DHc * Qc;

    const int lrow = lane & 15;            // q (B-frag n) / row index
    const int quad = lane >> 4;
    const int kq = quad * 8;

    // Q fragments (B-operand of S^T): rows i0 + wave*32 + t*16 + lrow
    f16x8 aq[2][4];
#pragma unroll
    for (int t = 0; t < 2; ++t)
#pragma unroll
        for (int kc = 0; kc < 4; ++kc)
            aq[t][kc] = *(const f16x8*)&Qh[(long)(i0 + wave * 32 + t * 16 + lrow) * 128 + kc * 32 + kq];

    float m_i[2] = {-1e30f, -1e30f}, l_i[2] = {0.0f, 0.0f};
    f32x4 o_acc[2][4] = {};   // D[m=q][n=d]: row q=quad*4+reg, col d=lane&15

    for (int j0 = 0; j0 < Qc; j0 += 128) {
        __syncthreads();   // prev iter's sK/sV/sRB reads complete
        for (int idx = tid; idx < 128 * 16; idx += 256) {
            int r = idx >> 4, c = (idx & 15) * 8;
            *(uint4*)&sK[r * LDL + c] = *(const uint4*)&Kh[(long)(j0 + r) * 128 + c];
        }
        for (int idx = tid; idx < 64 * 16; idx += 256) {
            int r = idx >> 4, c = (idx & 15) * 8;
            *(uint4*)&sV[r * LDL + c] = *(const uint4*)&Vh[(long)r * Qc + j0 + c];
        }
        if (tid < 128) {
            int j = j0 + tid;
            sRB[tid] = (j < Qc - 1) ? r_bias[(j + 1) * Nh + n] : 0.0f;
        }
        __syncthreads();

        // S^T: D[m=j][n=q], 128 j x 32 q per wave
        f32x4 s_acc[2][8] = {};
#pragma unroll
        for (int kc = 0; kc < 4; ++kc)
#pragma unroll
            for (int ni = 0; ni < 8; ++ni) {
                f16x8 bk = *(const f16x8*)&sK[(ni * 16 + lrow) * LDL + kc * 32 + kq];
                s_acc[0][ni] = __builtin_amdgcn_mfma_f32_16x16x32_f16(bk, aq[0][kc], s_acc[0][ni], 0, 0, 0);
                s_acc[1][ni] = __builtin_amdgcn_mfma_f32_16x16x32_f16(bk, aq[1][kc], s_acc[1][ni], 0, 0, 0);
            }

        // online softmax per q (= lane&15); j spread over regs (x4) and quads (x4)
        f16x4 pf[2][8];
        float alpha_t[2];
#pragma unroll
        for (int t = 0; t < 2; ++t) {
            float mx = -1e30f;
#pragma unroll
            for (int ni = 0; ni < 8; ++ni) {
                f32x4 rb4 = *(const f32x4*)&sRB[ni * 16 + quad * 4];
#pragma unroll
                for (int r = 0; r < 4; ++r) {
                    float v = (s_acc[t][ni][r] + rb4[r]) * ATT_SCALE;
                    s_acc[t][ni][r] = v;
                    mx = fmaxf(mx, v);
                }
            }
            mx = fmaxf(mx, __shfl_xor(mx, 16));
            mx = fmaxf(mx, __shfl_xor(mx, 32));
            float mn = fmaxf(m_i[t], mx);
            float alpha = __expf(m_i[t] - mn);
            float sm = 0.0f;
#pragma unroll
            for (int ni = 0; ni < 8; ++ni) {
                float e0 = __expf(s_acc[t][ni][0] - mn);
                float e1 = __expf(s_acc[t][ni][1] - mn);
                float e2 = __expf(s_acc[t][ni][2] - mn);
                float e3 = __expf(s_acc[t][ni][3] - mn);
                sm += (e0 + e1) + (e2 + e3);
                f16x4 pv; pv[0] = (f16)e0; pv[1] = (f16)e1; pv[2] = (f16)e2; pv[3] = (f16)e3;
                pf[t][ni] = pv;
            }
            sm += __shfl_xor(sm, 16);
            sm += __shfl_xor(sm, 32);
            l_i[t] = l_i[t] * alpha + sm;
            m_i[t] = mn;
            alpha_t[t] = alpha;
        }

        // rescale o_acc: broadcast alpha from lane (quad*4+r) of quad 0 group
#pragma unroll
        for (int t = 0; t < 2; ++t)
#pragma unroll
            for (int r = 0; r < 4; ++r) {
                float al = __shfl(alpha_t[t], quad * 4 + r);
#pragma unroll
                for (int dt = 0; dt < 4; ++dt) o_acc[t][dt][r] *= al;
            }

        // PV: D[m=q][n=d] += P[q][j] * V[j][d], K=16 chunks, P from registers
#pragma unroll
        for (int nj = 0; nj < 8; ++nj)
#pragma unroll
            for (int dt = 0; dt < 4; ++dt) {
                f16x4 bv = *(const f16x4*)&sV[(dt * 16 + lrow) * LDL + nj * 16 + quad * 4];
                o_acc[0][dt] = __builtin_amdgcn_mfma_f32_16x16x16f16(pf[0][nj], bv, o_acc[0][dt], 0, 0, 0);
                o_acc[1][dt] = __builtin_amdgcn_mfma_f32_16x16x16f16(pf[1][nj], bv, o_acc[1][dt], 0, 0, 0);
            }
    }

    // epilogue: avp[b][i][n*64+d] = O / l  (row q=quad*4+r, col d=lane&15)
#pragma unroll
    for (int t = 0; t < 2; ++t) {
        float linv = 1.0f / l_i[t];
#pragma unroll
        for (int r = 0; r < 4; ++r) {
            float li = __shfl(linv, quad * 4 + r);
            int i = i0 + wave * 32 + t * 16 + quad * 4 + r;
#pragma unroll
            for (int dt = 0; dt < 4; ++dt) {
                int d = dt * 16 + lrow;
                avp[((long)(b * Qc + i) << 10) + n * 64 + d] = (f16)(o_acc[t][dt][r] * li);
            }
        }
    }
}

// ---------------- residual + LayerNorm (f32 inputs, f32 output) ----------------
__global__ __launch_bounds__(256) void k_res_ln(const float* __restrict__ w, const float* __restrict__ ao,
                                                const float* __restrict__ gamma, const float* __restrict__ beta,
                                                float* __restrict__ out) {
    const long base = (long)blockIdx.x * 1024;
    const int tid = threadIdx.x;
    float x[4], s = 0.0f, s2 = 0.0f;
#pragma unroll
    for (int k = 0; k < 4; ++k) {
        int j = tid + k * 256;
        x[k] = w[base + j] + ao[base + j];
        s += x[k];
        s2 += x[k] * x[k];
    }
#pragma unroll
    for (int off = 32; off; off >>= 1) { s += __shfl_down(s, off); s2 += __shfl_down(s2, off); }
    __shared__ float rs[4], rs2[4];
    if ((tid & 63) == 0) { rs[tid >> 6] = s; rs2[tid >> 6] = s2; }
    __syncthreads();
    s = rs[0] + rs[1] + rs[2] + rs[3];
    s2 = rs2[0] + rs2[1] + rs2[2] + rs2[3];
    float mu = s * (1.0f / 1024.0f);
    float var = s2 * (1.0f / 1024.0f) - mu * mu;
    float inv = rsqrtf(var + 1e-5f);
#pragma unroll
    for (int k = 0; k < 4; ++k) {
        int j = tid + k * 256;
        out[base + j] = (x[k] - mu) * inv * gamma[j] + beta[j];
    }
}

extern "C" void kernel_launch(void* const* d_in, const int* in_sizes, int n_in,
                              void* d_out, int out_size, void* d_ws, size_t ws_size,
                              hipStream_t stream) {
    const float* w_in   = (const float*)d_in[0];
    const float* r_emb  = (const float*)d_in[1];
    const float* r_wb   = (const float*)d_in[2];
    const float* r_bias = (const float*)d_in[3];
    const float* Wq     = (const float*)d_in[4];
    const float* Wk     = (const float*)d_in[5];
    const float* Wv     = (const float*)d_in[6];
    const float* Wo     = (const float*)d_in[7];
    const float* ln_g   = (const float*)d_in[8];
    const float* ln_b   = (const float*)d_in[9];
    float* out = (float*)d_out;

    // workspace carve-out (56MB fixed + aliases)
    char* p = (char*)d_ws;
    auto alloc = [&](size_t bytes) { char* r = p; p += (bytes + 255) & ~(size_t)255; return r; };
    f16* wh = (f16*)alloc((size_t)BQ * Dc * 2);          // 8 MB
    f16* WT = (f16*)alloc((size_t)4 * Dc * Dc * 2);      // 8 MB: WqT,WkT,WvT,WoT (contiguous!)
    f16* Qt = (f16*)alloc((size_t)NHEAD * Qc * 128 * 2); // 16 MB
    f16* Kt = (f16*)alloc((size_t)NHEAD * Qc * 128 * 2); // 16 MB
    f16* vT = (f16*)alloc((size_t)BQ * Dc * 2);          // 8 MB [b][dcol][i]
    f16* WoT = WT + (size_t)3 * Dc * Dc;
    // aliases (liveness-checked): wh dead after QKV GEMM; Qt dead after flash
    f16*   avp = wh;                 // [b][i][1024] f16
    float* ao  = (float*)Qt;         // 16 MB fp32

    // 1. f32->f16 of w (8/thread)
    k_f2h<<<(BQ * Dc) / (256 * 8), 256, 0, stream>>>(w_in, wh);

    // 2. transpose 4 weights in one dispatch (f32 -> f16); WqT/WkT/WvT contiguous = B of QKV GEMM
    Ptr4 srcs{{Wq, Wk, Wv, Wo}};
    k_transpose4<<<dim3(32, 32, 4), dim3(32, 8), 0, stream>>>(srcs, WT);

    // 3. rel-shifted r_emb -> Kt[...][64:128] (independent of GEMMs)
    k_fill_remb<<<(NHEAD * Qc * 8) / 256, 256, 0, stream>>>(r_emb, Kt);

    // 4. fused QKV projection: N=3072, scatter epilogue to Qt/Kt/vT (768 blocks)
    k_gemm_nt<128, 128, 32, 2, 2, 5><<<dim3(3 * Dc / 128, BQ / 128), 256, 0, stream>>>(
        wh, WT, nullptr, r_wb, Qt, Kt, vT, Dc, Dc, 0, Dc);

    // 5. fused attention: S^T -> online softmax(+r_bias shift) -> PV, writes avp
    k_flash<<<dim3(Qc / 128, NHEAD), 256, 0, stream>>>(Qt, Kt, vT, r_bias, avp);

    // 6. attn_out = avp @ Wo^T (64x128 tile -> 512 blocks; fp32 out into aliased ao)
    k_gemm_nt<64, 128, 32, 2, 2, 1><<<dim3(Dc / 128, BQ / 64), 256, 0, stream>>>(
        avp, WoT, ao, nullptr, nullptr, nullptr, nullptr, Dc, Dc, Dc, Dc);

    // 7. out = LayerNorm(w + attn_out), fp32 output
    k_res_ln<<<BQ, 256, 0, stream>>>(w_in, ao, ln_g, ln_b, out);
}